// Round 6
// baseline (114.461 us; speedup 1.0000x reference)
//
#include <hip/hip_runtime.h>

#define DD 64
#define LL 200
#define LP 256     // LL padded to multiple of 128
#define GG 6
#define LAMBDA 0.001f

typedef __attribute__((ext_vector_type(8))) short s8v;   // 8 bf16 (4 VGPRs)
typedef __attribute__((ext_vector_type(4))) float f4v;   // MFMA accumulator

__device__ __forceinline__ float wave_reduce_sum(float v) {
    #pragma unroll
    for (int off = 32; off > 0; off >>= 1)
        v += __shfl_xor(v, off, 64);
    return v;
}

__device__ __forceinline__ unsigned short f2bf(float f) {
    union { float f; unsigned int u; } v; v.f = f;
    return (unsigned short)((v.u + 0x7FFFu + ((v.u >> 16) & 1u)) >> 16);  // RNE
}

//======================================================================
// Kernel 0a: emb_item fp32 [V][64] -> bf16 chunk-major [4][V][16].
// Each 16-dim chunk slice is 3.2MB -> fits one XCD's 4MB L2.
//======================================================================
__global__ __launch_bounds__(256)
void convert_emb_kernel(const float* __restrict__ in,
                        unsigned short* __restrict__ out, int V)
{
    const int stride = gridDim.x * blockDim.x;
    const int total = V * 4;
    for (int i = blockIdx.x * blockDim.x + threadIdx.x; i < total; i += stride) {
        const int v = i >> 2, c = i & 3;
        const float4 f0 = *(const float4*)&in[(size_t)v * 64 + c * 16];
        const float4 f1 = *(const float4*)&in[(size_t)v * 64 + c * 16 + 4];
        const float4 f2 = *(const float4*)&in[(size_t)v * 64 + c * 16 + 8];
        const float4 f3 = *(const float4*)&in[(size_t)v * 64 + c * 16 + 12];
        unsigned short* o = out + ((size_t)c * V + v) * 16;
        s8v a, b;
        a[0]=(short)f2bf(f0.x); a[1]=(short)f2bf(f0.y); a[2]=(short)f2bf(f0.z); a[3]=(short)f2bf(f0.w);
        a[4]=(short)f2bf(f1.x); a[5]=(short)f2bf(f1.y); a[6]=(short)f2bf(f1.z); a[7]=(short)f2bf(f1.w);
        b[0]=(short)f2bf(f2.x); b[1]=(short)f2bf(f2.y); b[2]=(short)f2bf(f2.z); b[3]=(short)f2bf(f2.w);
        b[4]=(short)f2bf(f3.x); b[5]=(short)f2bf(f3.y); b[6]=(short)f2bf(f3.z); b[7]=(short)f2bf(f3.w);
        *(s8v*)&o[0] = a;
        *(s8v*)&o[8] = b;
    }
}

//======================================================================
// Kernel 0b: convert all 4 MLP weight matrices to frag-ordered bf16
// blobs (one 16B slot per (ks,nt,lane)). 9216 slots total.
//  layout: [ut_w1: 4096][ut_w2: 1024][it_w1: 3072][it_w2: 1024]
//======================================================================
__global__ __launch_bounds__(256)
void prep_weights_kernel(const float* __restrict__ ut_w1, const float* __restrict__ ut_w2,
                         const float* __restrict__ it_w1, const float* __restrict__ it_w2,
                         unsigned short* __restrict__ blob)
{
    const int s = blockIdx.x * 256 + threadIdx.x;   // 0..9215
    if (s >= 9216) return;
    const float* src; int K, NT, r, k8; size_t obase;
    if (s < 4096)      { src = ut_w1; K = 256; NT = 8; r = s >> 5;          k8 = s & 31;          obase = 0; }
    else if (s < 5120) { src = ut_w2; K = 128; NT = 4; r = (s-4096) >> 4;   k8 = (s-4096) & 15;   obase = 4096; }
    else if (s < 8192) { src = it_w1; K = 192; NT = 8; r = (s-5120) / 24;   k8 = (s-5120) % 24;   obase = 5120; }
    else               { src = it_w2; K = 128; NT = 4; r = (s-8192) >> 4;   k8 = (s-8192) & 15;   obase = 8192; }
    const int k = k8 * 8;
    const float4 f0 = *(const float4*)&src[(size_t)r * K + k];
    const float4 f1 = *(const float4*)&src[(size_t)r * K + k + 4];
    const int ks = k >> 5, lg = (k >> 3) & 3;
    const int lp = lg * 16 + (r & 15), nt = r >> 4;
    const size_t slot = obase + (size_t)(ks * NT + nt) * 64 + lp;
    s8v wv;
    wv[0]=(short)f2bf(f0.x); wv[1]=(short)f2bf(f0.y); wv[2]=(short)f2bf(f0.z); wv[3]=(short)f2bf(f0.w);
    wv[4]=(short)f2bf(f1.x); wv[5]=(short)f2bf(f1.y); wv[6]=(short)f2bf(f1.z); wv[7]=(short)f2bf(f1.w);
    *(s8v*)&blob[slot * 8] = wv;
}

//======================================================================
// Kernel 1: history pooling, d-chunk split for L2 residency.
// grid = B blocks; block bi: chunk = bi&3 (matches XCD = bi&7 mod 4),
// rows (bi>>2)*4 + wave. Wave: 8 groups x 8 lanes; lane = 2 dims (4B).
//======================================================================
__global__ __launch_bounds__(256)
void hist_pool_kernel(const int* __restrict__ history,
                      const float* __restrict__ ts_diff,
                      const unsigned short* __restrict__ emb_c,  // [4][V][16]
                      float* __restrict__ hist_out, int V, int B)
{
    const int wave = threadIdx.x >> 6;
    const int lane = threadIdx.x & 63;
    const int bi = blockIdx.x;
    const int chunk = bi & 3;
    const int b = (bi >> 2) * 4 + wave;
    const int grp = lane >> 3;    // entry subgroup 0..7
    const int c2 = lane & 7;      // dim-pair within 16-dim chunk

    __shared__ float2 s_p[4][LP];

    const int*   hrow = history + (size_t)b * LL;
    const float* trow = ts_diff + (size_t)b * LL;

    float wpart = 0.f;
    #pragma unroll
    for (int l = lane; l < LP; l += 64) {
        int idx = 0; float w = 0.f;
        if (l < LL) {
            const int raw = hrow[l];
            if (raw > 0) { w = __expf(-LAMBDA * trow[l]); idx = raw; }
        }
        s_p[wave][l] = make_float2(w, __int_as_float(idx));
        wpart += w;
    }
    const float wsum = wave_reduce_sum(wpart);
    __syncthreads();

    const unsigned short* base = emb_c + (size_t)chunk * V * 16 + c2 * 2;
    float a0 = 0.f, a1 = 0.f;
    #pragma unroll
    for (int l0 = 0; l0 < LP; l0 += 128) {
        unsigned int e[16]; float w[16];
        #pragma unroll
        for (int i = 0; i < 16; ++i) {
            const float2 p = s_p[wave][l0 + i * 8 + grp];
            w[i] = p.x;
            e[i] = *(const unsigned int*)&base[(size_t)__float_as_int(p.y) * 16];
        }
        #pragma unroll
        for (int i = 0; i < 16; ++i) {
            a0 = fmaf(w[i], __uint_as_float(e[i] << 16), a0);
            a1 = fmaf(w[i], __uint_as_float(e[i] & 0xffff0000u), a1);
        }
    }
    // reduce across the 8 entry-subgroups (lanes differing in bits 3,4,5)
    #pragma unroll
    for (int off = 8; off <= 32; off <<= 1) {
        a0 += __shfl_xor(a0, off, 64);
        a1 += __shfl_xor(a1, off, 64);
    }
    if (grp == 0) {
        const float inv = 1.f / (wsum + 1e-8f);
        *(float2*)&hist_out[(size_t)b * DD + chunk * 16 + c2 * 2] =
            make_float2(a0 * inv, a1 * inv);
    }
}

//======================================================================
// X/H fragment slot: A-operand layout for mfma_f32_16x16x32_bf16:
//   lane' = ((d>>3)&3)*16 + (r&15),  j = d&7,  k-step = d>>5
//======================================================================
#define PUT_FRAG(buf, NKS, r, d, val)                                   \
    do {                                                                \
        const int _mt = (r) >> 4, _ks = (d) >> 5;                       \
        const int _lp = (((d) >> 3) & 3) * 16 + ((r) & 15);             \
        (buf)[(((_mt) * (NKS) + _ks) * 64 + _lp) * 8 + ((d) & 7)] = f2bf(val); \
    } while (0)

//======================================================================
// Kernel 2: user tower (256 -> 128 -> 64), 64 rows/block, 8 waves.
// Weights staged as pure 16B copies from pre-converted blob.
//======================================================================
__global__ __launch_bounds__(512)
void user_tower_kernel(
    const int* __restrict__ user_id, const int* __restrict__ top_genres,
    const float* __restrict__ hist_pool,
    const float* __restrict__ u_avg, const float* __restrict__ activity,
    const float* __restrict__ emb_genre, const float* __restrict__ emb_user,
    const float* __restrict__ cont_w, const float* __restrict__ cont_b,
    const unsigned short* __restrict__ wblob,
    const float* __restrict__ b1,
    const float* __restrict__ gam, const float* __restrict__ bet,
    const float* __restrict__ b2,
    float* __restrict__ out, int B)
{
    const int tid = threadIdx.x, wave = tid >> 6, lane = tid & 63;
    const int r0 = blockIdx.x * 64;

    __shared__ __align__(16) unsigned short sW1[8 * 8 * 64 * 8];  // 64KB frag-order
    __shared__ __align__(16) unsigned short sW2[4 * 4 * 64 * 8];  // 16KB frag-order
    __shared__ __align__(16) unsigned char  sC[64 * 128 * 4];     // 32KB: Xfrag -> y -> o
    __shared__ __align__(16) unsigned short sHf[4 * 4 * 64 * 8];  // 16KB h frag-order

    unsigned short* sXf = (unsigned short*)sC;
    float* sY = (float*)sC;
    float* sO = (float*)sC;

    //---- stage W1/W2 from blob (coalesced 16B copies, no conversion) ----
    #pragma unroll
    for (int i = 0; i < 8; ++i)
        *(s8v*)&sW1[(tid + i * 512) * 8] = *(const s8v*)&wblob[(tid + i * 512) * 8];
    #pragma unroll
    for (int i = 0; i < 2; ++i)
        *(s8v*)&sW2[(tid + i * 512) * 8] = *(const s8v*)&wblob[(4096 + tid + i * 512) * 8];

    //---- build X features (wave -> rows wave*8..+7) ----
    #pragma unroll 2
    for (int i = 0; i < 8; ++i) {
        const int r = wave * 8 + i, b = r0 + r;
        const float ue = emb_user[(size_t)user_id[b] * DD + lane];
        const float hp = hist_pool[(size_t)b * DD + lane];
        const int* grow = top_genres + (size_t)b * GG;
        float gacc = 0.f, gw = 0.f;
        #pragma unroll
        for (int g = 0; g < GG; ++g) {
            const int idx = grow[g];
            const float m = (idx > 0) ? 1.f : 0.f;
            gacc = fmaf(m, emb_genre[idx * DD + lane], gacc);
            gw += m;
        }
        const float ug = gacc / (gw + 1e-8f);
        float uc = fmaf(u_avg[b], cont_w[lane * 2 + 0],
                   fmaf(activity[b], cont_w[lane * 2 + 1], cont_b[lane]));
        uc = fmaxf(uc, 0.f);
        PUT_FRAG(sXf, 8, r, lane, ue);
        PUT_FRAG(sXf, 8, r, 64 + lane, hp);
        PUT_FRAG(sXf, 8, r, 128 + lane, ug);
        PUT_FRAG(sXf, 8, r, 192 + lane, uc);
    }
    __syncthreads();

    //---- L1 MFMA: M=64, N=128, K=256. wave: mh=wave>>2, nh=wave&3 ----
    const int mh = wave >> 2, nh = wave & 3;
    f4v acc[2][2];
    const f4v zero4 = {0.f, 0.f, 0.f, 0.f};
    #pragma unroll
    for (int a = 0; a < 2; ++a)
        #pragma unroll
        for (int c = 0; c < 2; ++c) acc[a][c] = zero4;

    #pragma unroll
    for (int ks = 0; ks < 8; ++ks) {
        s8v av[2], bv[2];
        #pragma unroll
        for (int ml = 0; ml < 2; ++ml)
            av[ml] = *(const s8v*)&sXf[(((mh * 2 + ml) * 8 + ks) * 64 + lane) * 8];
        #pragma unroll
        for (int nl = 0; nl < 2; ++nl)
            bv[nl] = *(const s8v*)&sW1[((ks * 8 + nh * 2 + nl) * 64 + lane) * 8];
        #pragma unroll
        for (int ml = 0; ml < 2; ++ml)
            #pragma unroll
            for (int nl = 0; nl < 2; ++nl)
                acc[ml][nl] = __builtin_amdgcn_mfma_f32_16x16x32_bf16(av[ml], bv[nl], acc[ml][nl], 0, 0, 0);
    }
    __syncthreads();

    //---- y = acc + b1 -> sY [64][128] fp32 ----
    #pragma unroll
    for (int ml = 0; ml < 2; ++ml) {
        #pragma unroll
        for (int nl = 0; nl < 2; ++nl) {
            const int n = (nh * 2 + nl) * 16 + (lane & 15);
            const float bb = b1[n];
            #pragma unroll
            for (int rg = 0; rg < 4; ++rg) {
                const int m = (mh * 2 + ml) * 16 + (lane >> 4) * 4 + rg;
                sY[m * 128 + n] = acc[ml][nl][rg] + bb;
            }
        }
    }
    __syncthreads();

    //---- LN + ReLU -> sHf (rows wave*8..+7) ----
    {
        const float g0 = gam[lane], g1 = gam[lane + 64];
        const float e0 = bet[lane], e1 = bet[lane + 64];
        for (int i = 0; i < 8; ++i) {
            const int r = wave * 8 + i;
            const float a = sY[r * 128 + lane];
            const float c = sY[r * 128 + 64 + lane];
            const float mean = wave_reduce_sum(a + c) * (1.f / 128.f);
            const float da = a - mean, dc = c - mean;
            const float var = wave_reduce_sum(da * da + dc * dc) * (1.f / 128.f);
            const float rstd = rsqrtf(var + 1e-5f);
            const float h0 = fmaxf(fmaf(da * rstd, g0, e0), 0.f);
            const float h1 = fmaxf(fmaf(dc * rstd, g1, e1), 0.f);
            PUT_FRAG(sHf, 4, r, lane, h0);
            PUT_FRAG(sHf, 4, r, 64 + lane, h1);
        }
    }
    __syncthreads();

    //---- L2 MFMA: M=64, N=64, K=128. wave: 2 mtiles x 1 ntile ----
    f4v acc2[2];
    acc2[0] = zero4; acc2[1] = zero4;
    #pragma unroll
    for (int ks = 0; ks < 4; ++ks) {
        s8v av[2], bv;
        #pragma unroll
        for (int ml = 0; ml < 2; ++ml)
            av[ml] = *(const s8v*)&sHf[(((mh * 2 + ml) * 4 + ks) * 64 + lane) * 8];
        bv = *(const s8v*)&sW2[((ks * 4 + nh) * 64 + lane) * 8];
        #pragma unroll
        for (int ml = 0; ml < 2; ++ml)
            acc2[ml] = __builtin_amdgcn_mfma_f32_16x16x32_bf16(av[ml], bv, acc2[ml], 0, 0, 0);
    }
    #pragma unroll
    for (int ml = 0; ml < 2; ++ml) {
        const int n = nh * 16 + (lane & 15);
        const float bb = b2[n];
        #pragma unroll
        for (int rg = 0; rg < 4; ++rg) {
            const int m = (mh * 2 + ml) * 16 + (lane >> 4) * 4 + rg;
            sO[m * 64 + n] = acc2[ml][rg] + bb;
        }
    }
    __syncthreads();

    //---- l2norm + store ----
    for (int i = 0; i < 8; ++i) {
        const int r = wave * 8 + i;
        const float o = sO[r * 64 + lane];
        const float nrm = sqrtf(wave_reduce_sum(o * o));
        out[(size_t)(r0 + r) * DD + lane] = o / fmaxf(nrm, 1e-12f);
    }
}

//======================================================================
// Kernel 3: item tower (192 -> 128 -> 64), 64 rows/block, 8 waves.
//======================================================================
__global__ __launch_bounds__(512)
void item_tower_kernel(
    const int* __restrict__ item_id, const int* __restrict__ tmdb_genres,
    const float* __restrict__ rel_year, const float* __restrict__ i_avg,
    const float* __restrict__ revenue,
    const float* __restrict__ emb_item, const float* __restrict__ emb_genre,
    const float* __restrict__ cont_w, const float* __restrict__ cont_b,
    const unsigned short* __restrict__ wblob,
    const float* __restrict__ b1,
    const float* __restrict__ gam, const float* __restrict__ bet,
    const float* __restrict__ b2,
    float* __restrict__ out, int B)
{
    const int tid = threadIdx.x, wave = tid >> 6, lane = tid & 63;
    const int r0 = blockIdx.x * 64;

    __shared__ __align__(16) unsigned short sW1[6 * 8 * 64 * 8];  // 48KB
    __shared__ __align__(16) unsigned short sW2[4 * 4 * 64 * 8];  // 16KB
    __shared__ __align__(16) unsigned char  sC[64 * 128 * 4];     // 32KB
    __shared__ __align__(16) unsigned short sHf[4 * 4 * 64 * 8];  // 16KB

    unsigned short* sXf = (unsigned short*)sC;
    float* sY = (float*)sC;
    float* sO = (float*)sC;

    //---- stage W1/W2 from blob ----
    #pragma unroll
    for (int i = 0; i < 6; ++i)
        *(s8v*)&sW1[(tid + i * 512) * 8] = *(const s8v*)&wblob[(5120 + tid + i * 512) * 8];
    #pragma unroll
    for (int i = 0; i < 2; ++i)
        *(s8v*)&sW2[(tid + i * 512) * 8] = *(const s8v*)&wblob[(8192 + tid + i * 512) * 8];

    //---- build X features ----
    #pragma unroll 2
    for (int i = 0; i < 8; ++i) {
        const int r = wave * 8 + i, b = r0 + r;
        const float ie = emb_item[(size_t)item_id[b] * DD + lane];
        const int* grow = tmdb_genres + (size_t)b * GG;
        float gacc = 0.f, gw = 0.f;
        #pragma unroll
        for (int g = 0; g < GG; ++g) {
            const int idx = grow[g];
            const float m = (idx > 0) ? 1.f : 0.f;
            gacc = fmaf(m, emb_genre[idx * DD + lane], gacc);
            gw += m;
        }
        const float ig = gacc / (gw + 1e-8f);
        float ic = fmaf(rel_year[b], cont_w[lane * 3 + 0],
                   fmaf(i_avg[b],   cont_w[lane * 3 + 1],
                   fmaf(revenue[b], cont_w[lane * 3 + 2], cont_b[lane])));
        ic = fmaxf(ic, 0.f);
        PUT_FRAG(sXf, 6, r, lane, ie);
        PUT_FRAG(sXf, 6, r, 64 + lane, ig);
        PUT_FRAG(sXf, 6, r, 128 + lane, ic);
    }
    __syncthreads();

    //---- L1 MFMA: M=64, N=128, K=192 ----
    const int mh = wave >> 2, nh = wave & 3;
    f4v acc[2][2];
    const f4v zero4 = {0.f, 0.f, 0.f, 0.f};
    #pragma unroll
    for (int a = 0; a < 2; ++a)
        #pragma unroll
        for (int c = 0; c < 2; ++c) acc[a][c] = zero4;

    #pragma unroll
    for (int ks = 0; ks < 6; ++ks) {
        s8v av[2], bv[2];
        #pragma unroll
        for (int ml = 0; ml < 2; ++ml)
            av[ml] = *(const s8v*)&sXf[(((mh * 2 + ml) * 6 + ks) * 64 + lane) * 8];
        #pragma unroll
        for (int nl = 0; nl < 2; ++nl)
            bv[nl] = *(const s8v*)&sW1[((ks * 8 + nh * 2 + nl) * 64 + lane) * 8];
        #pragma unroll
        for (int ml = 0; ml < 2; ++ml)
            #pragma unroll
            for (int nl = 0; nl < 2; ++nl)
                acc[ml][nl] = __builtin_amdgcn_mfma_f32_16x16x32_bf16(av[ml], bv[nl], acc[ml][nl], 0, 0, 0);
    }
    __syncthreads();

    #pragma unroll
    for (int ml = 0; ml < 2; ++ml) {
        #pragma unroll
        for (int nl = 0; nl < 2; ++nl) {
            const int n = (nh * 2 + nl) * 16 + (lane & 15);
            const float bb = b1[n];
            #pragma unroll
            for (int rg = 0; rg < 4; ++rg) {
                const int m = (mh * 2 + ml) * 16 + (lane >> 4) * 4 + rg;
                sY[m * 128 + n] = acc[ml][nl][rg] + bb;
            }
        }
    }
    __syncthreads();

    {
        const float g0 = gam[lane], g1 = gam[lane + 64];
        const float e0 = bet[lane], e1 = bet[lane + 64];
        for (int i = 0; i < 8; ++i) {
            const int r = wave * 8 + i;
            const float a = sY[r * 128 + lane];
            const float c = sY[r * 128 + 64 + lane];
            const float mean = wave_reduce_sum(a + c) * (1.f / 128.f);
            const float da = a - mean, dc = c - mean;
            const float var = wave_reduce_sum(da * da + dc * dc) * (1.f / 128.f);
            const float rstd = rsqrtf(var + 1e-5f);
            const float h0 = fmaxf(fmaf(da * rstd, g0, e0), 0.f);
            const float h1 = fmaxf(fmaf(dc * rstd, g1, e1), 0.f);
            PUT_FRAG(sHf, 4, r, lane, h0);
            PUT_FRAG(sHf, 4, r, 64 + lane, h1);
        }
    }
    __syncthreads();

    f4v acc2[2];
    acc2[0] = zero4; acc2[1] = zero4;
    #pragma unroll
    for (int ks = 0; ks < 4; ++ks) {
        s8v av[2], bv;
        #pragma unroll
        for (int ml = 0; ml < 2; ++ml)
            av[ml] = *(const s8v*)&sHf[(((mh * 2 + ml) * 4 + ks) * 64 + lane) * 8];
        bv = *(const s8v*)&sW2[((ks * 4 + nh) * 64 + lane) * 8];
        #pragma unroll
        for (int ml = 0; ml < 2; ++ml)
            acc2[ml] = __builtin_amdgcn_mfma_f32_16x16x32_bf16(av[ml], bv, acc2[ml], 0, 0, 0);
    }
    #pragma unroll
    for (int ml = 0; ml < 2; ++ml) {
        const int n = nh * 16 + (lane & 15);
        const float bb = b2[n];
        #pragma unroll
        for (int rg = 0; rg < 4; ++rg) {
            const int m = (mh * 2 + ml) * 16 + (lane >> 4) * 4 + rg;
            sO[m * 64 + n] = acc2[ml][rg] + bb;
        }
    }
    __syncthreads();

    for (int i = 0; i < 8; ++i) {
        const int r = wave * 8 + i;
        const float o = sO[r * 64 + lane];
        const float nrm = sqrtf(wave_reduce_sum(o * o));
        out[(size_t)B * DD + (size_t)(r0 + r) * DD + lane] = o / fmaxf(nrm, 1e-12f);
    }
}

extern "C" void kernel_launch(void* const* d_in, const int* in_sizes, int n_in,
                              void* d_out, int out_size, void* d_ws, size_t ws_size,
                              hipStream_t stream) {
    const int*   user_id     = (const int*)  d_in[0];
    const int*   history     = (const int*)  d_in[1];
    const int*   top_genres  = (const int*)  d_in[2];
    const int*   item_id     = (const int*)  d_in[3];
    const int*   tmdb_genres = (const int*)  d_in[4];
    const float* ts_diff     = (const float*)d_in[5];
    const float* u_avg       = (const float*)d_in[6];
    const float* activity    = (const float*)d_in[7];
    const float* rel_year    = (const float*)d_in[8];
    const float* i_avg       = (const float*)d_in[9];
    const float* revenue     = (const float*)d_in[10];
    const float* emb_item    = (const float*)d_in[11];
    const float* emb_genre   = (const float*)d_in[12];
    const float* emb_user    = (const float*)d_in[13];
    const float* ut_cont_w   = (const float*)d_in[14];
    const float* ut_cont_b   = (const float*)d_in[15];
    const float* ut_w1       = (const float*)d_in[16];
    const float* ut_b1       = (const float*)d_in[17];
    const float* ut_g        = (const float*)d_in[18];
    const float* ut_be       = (const float*)d_in[19];
    const float* ut_w2       = (const float*)d_in[20];
    const float* ut_b2       = (const float*)d_in[21];
    const float* it_cont_w   = (const float*)d_in[22];
    const float* it_cont_b   = (const float*)d_in[23];
    const float* it_w1       = (const float*)d_in[24];
    const float* it_b1       = (const float*)d_in[25];
    const float* it_g        = (const float*)d_in[26];
    const float* it_be       = (const float*)d_in[27];
    const float* it_w2       = (const float*)d_in[28];
    const float* it_b2       = (const float*)d_in[29];

    const int B = in_sizes[0];                 // 16384
    const int V = in_sizes[11] / DD;           // 100001

    // workspace layout
    float* hist_pool = (float*)d_ws;                                  // B*64*4 = 4MB
    size_t off = (size_t)B * DD * sizeof(float);
    unsigned short* emb_c = (unsigned short*)((char*)d_ws + off);     // 4*V*16*2 = 12.8MB
    off += (size_t)4 * V * 16 * sizeof(unsigned short);
    off = (off + 255) & ~(size_t)255;
    unsigned short* wblob = (unsigned short*)((char*)d_ws + off);     // 9216*16B = 144KB

    hipLaunchKernelGGL(convert_emb_kernel, dim3(1024), dim3(256), 0, stream,
        emb_item, emb_c, V);

    hipLaunchKernelGGL(prep_weights_kernel, dim3(36), dim3(256), 0, stream,
        ut_w1, ut_w2, it_w1, it_w2, wblob);

    hipLaunchKernelGGL(hist_pool_kernel, dim3(B), dim3(256), 0, stream,
        history, ts_diff, emb_c, hist_pool, V, B);

    hipLaunchKernelGGL(user_tower_kernel, dim3(B / 64), dim3(512), 0, stream,
        user_id, top_genres, hist_pool, u_avg, activity,
        emb_genre, emb_user, ut_cont_w, ut_cont_b,
        wblob, ut_b1, ut_g, ut_be, ut_b2,
        (float*)d_out, B);

    hipLaunchKernelGGL(item_tower_kernel, dim3(B / 64), dim3(512), 0, stream,
        item_id, tmdb_genres, rel_year, i_avg, revenue,
        emb_item, emb_genre, it_cont_w, it_cont_b,
        wblob, it_b1, it_g, it_be, it_b2,
        (float*)d_out, B);
}

// Round 7
// 86.255 us; speedup vs baseline: 1.3270x; 1.3270x over previous
//
#include <hip/hip_runtime.h>

#define DD 64
#define LL 200
#define LP 256     // LL padded
#define GG 6
#define LAMBDA 0.001f
#define CONV_BLOCKS 1024

typedef __attribute__((ext_vector_type(8))) short s8v;   // 8 bf16 (4 VGPRs)
typedef __attribute__((ext_vector_type(4))) float f4v;   // MFMA accumulator

__device__ __forceinline__ float wave_reduce_sum(float v) {
    #pragma unroll
    for (int off = 32; off > 0; off >>= 1)
        v += __shfl_xor(v, off, 64);
    return v;
}

__device__ __forceinline__ unsigned short f2bf(float f) {
    union { float f; unsigned int u; } v; v.f = f;
    return (unsigned short)((v.u + 0x7FFFu + ((v.u >> 16) & 1u)) >> 16);  // RNE
}

//======================================================================
// Kernel 0: fused prep — blocks [0,1024): emb_item fp32 -> bf16 rows;
// blocks [1024,1060): 4 MLP weight matrices -> frag-ordered bf16 blob.
//  blob layout: [ut_w1: 4096][ut_w2: 1024][it_w1: 3072][it_w2: 1024]
//======================================================================
__global__ __launch_bounds__(256)
void prep_kernel(const float* __restrict__ emb_item,
                 const float* __restrict__ ut_w1, const float* __restrict__ ut_w2,
                 const float* __restrict__ it_w1, const float* __restrict__ it_w2,
                 unsigned short* __restrict__ emb_out,
                 unsigned short* __restrict__ blob, int n4)
{
    if (blockIdx.x < CONV_BLOCKS) {
        const int stride = CONV_BLOCKS * 256;
        for (int i = blockIdx.x * 256 + threadIdx.x; i < n4; i += stride) {
            const float4 f = *(const float4*)&emb_item[(size_t)i * 4];
            ushort4 o;
            o.x = f2bf(f.x); o.y = f2bf(f.y); o.z = f2bf(f.z); o.w = f2bf(f.w);
            *(ushort4*)&emb_out[(size_t)i * 4] = o;
        }
        return;
    }
    const int s = (blockIdx.x - CONV_BLOCKS) * 256 + threadIdx.x;   // 0..9215
    if (s >= 9216) return;
    const float* src; int K, NT, r, k8; size_t obase;
    if (s < 4096)      { src = ut_w1; K = 256; NT = 8; r = s >> 5;          k8 = s & 31;          obase = 0; }
    else if (s < 5120) { src = ut_w2; K = 128; NT = 4; r = (s-4096) >> 4;   k8 = (s-4096) & 15;   obase = 4096; }
    else if (s < 8192) { src = it_w1; K = 192; NT = 8; r = (s-5120) / 24;   k8 = (s-5120) % 24;   obase = 5120; }
    else               { src = it_w2; K = 128; NT = 4; r = (s-8192) >> 4;   k8 = (s-8192) & 15;   obase = 8192; }
    const int k = k8 * 8;
    const float4 f0 = *(const float4*)&src[(size_t)r * K + k];
    const float4 f1 = *(const float4*)&src[(size_t)r * K + k + 4];
    const int ks = k >> 5, lg = (k >> 3) & 3;
    const int lp = lg * 16 + (r & 15), nt = r >> 4;
    const size_t slot = obase + (size_t)(ks * NT + nt) * 64 + lp;
    s8v wv;
    wv[0]=(short)f2bf(f0.x); wv[1]=(short)f2bf(f0.y); wv[2]=(short)f2bf(f0.z); wv[3]=(short)f2bf(f0.w);
    wv[4]=(short)f2bf(f1.x); wv[5]=(short)f2bf(f1.y); wv[6]=(short)f2bf(f1.z); wv[7]=(short)f2bf(f1.w);
    *(s8v*)&blob[slot * 8] = wv;
}

//======================================================================
// Kernel 1: history pooling from bf16 table (row-major [V][64]).
// One wave per row; 16-lane groups; 8B/lane per entry; 16 in flight.
//======================================================================
__global__ __launch_bounds__(256)
void hist_pool_kernel(const int* __restrict__ history,
                      const float* __restrict__ ts_diff,
                      const unsigned short* __restrict__ emb_bf16,
                      float* __restrict__ hist_out, int B)
{
    const int wave = threadIdx.x >> 6;
    const int lane = threadIdx.x & 63;
    const int b = blockIdx.x * 4 + wave;
    const int g = lane >> 4;      // entry subgroup 0..3
    const int c = lane & 15;      // 4-dim chunk within row

    __shared__ float2 s_p[4][LP];

    const int*   hrow = history + (size_t)b * LL;
    const float* trow = ts_diff + (size_t)b * LL;

    float wpart = 0.f;
    #pragma unroll
    for (int l = lane; l < LP; l += 64) {
        int idx = 0; float w = 0.f;
        if (l < LL) {
            const int raw = hrow[l];
            if (raw > 0) { w = __expf(-LAMBDA * trow[l]); idx = raw; }
        }
        s_p[wave][l] = make_float2(w, __int_as_float(idx));
        wpart += w;
    }
    const float wsum = wave_reduce_sum(wpart);
    __syncthreads();

    float4 acc = make_float4(0.f, 0.f, 0.f, 0.f);
    #pragma unroll 1
    for (int l0 = 0; l0 < LP; l0 += 64) {
        uint2 e[16]; float w[16];
        #pragma unroll
        for (int i = 0; i < 16; ++i) {
            const float2 p = s_p[wave][l0 + i * 4 + g];
            w[i] = p.x;
            e[i] = *(const uint2*)&emb_bf16[(size_t)__float_as_int(p.y) * DD + c * 4];
        }
        #pragma unroll
        for (int i = 0; i < 16; ++i) {
            const float e0 = __uint_as_float(e[i].x << 16);
            const float e1 = __uint_as_float(e[i].x & 0xffff0000u);
            const float e2 = __uint_as_float(e[i].y << 16);
            const float e3 = __uint_as_float(e[i].y & 0xffff0000u);
            acc.x = fmaf(w[i], e0, acc.x);
            acc.y = fmaf(w[i], e1, acc.y);
            acc.z = fmaf(w[i], e2, acc.z);
            acc.w = fmaf(w[i], e3, acc.w);
        }
    }
    #pragma unroll
    for (int off = 16; off <= 32; off <<= 1) {
        acc.x += __shfl_xor(acc.x, off, 64);
        acc.y += __shfl_xor(acc.y, off, 64);
        acc.z += __shfl_xor(acc.z, off, 64);
        acc.w += __shfl_xor(acc.w, off, 64);
    }
    if (g == 0) {
        const float inv = 1.f / (wsum + 1e-8f);
        float4 o = make_float4(acc.x * inv, acc.y * inv, acc.z * inv, acc.w * inv);
        *(float4*)&hist_out[(size_t)b * DD + c * 4] = o;
    }
}

//======================================================================
// X/H fragment slot: A-operand layout for mfma_f32_16x16x32_bf16:
//   lane' = ((d>>3)&3)*16 + (r&15),  j = d&7,  k-step = d>>5
//======================================================================
#define PUT_FRAG(buf, NKS, r, d, val)                                   \
    do {                                                                \
        const int _mt = (r) >> 4, _ks = (d) >> 5;                       \
        const int _lp = (((d) >> 3) & 3) * 16 + ((r) & 15);             \
        (buf)[(((_mt) * (NKS) + _ks) * 64 + _lp) * 8 + ((d) & 7)] = f2bf(val); \
    } while (0)

//======================================================================
// Kernel 2: user tower (256 -> 128 -> 64), 64 rows/block, 8 waves.
//======================================================================
__global__ __launch_bounds__(512)
void user_tower_kernel(
    const int* __restrict__ user_id, const int* __restrict__ top_genres,
    const float* __restrict__ hist_pool,
    const float* __restrict__ u_avg, const float* __restrict__ activity,
    const float* __restrict__ emb_genre, const float* __restrict__ emb_user,
    const float* __restrict__ cont_w, const float* __restrict__ cont_b,
    const unsigned short* __restrict__ wblob,
    const float* __restrict__ b1,
    const float* __restrict__ gam, const float* __restrict__ bet,
    const float* __restrict__ b2,
    float* __restrict__ out, int B)
{
    const int tid = threadIdx.x, wave = tid >> 6, lane = tid & 63;
    const int r0 = blockIdx.x * 64;

    __shared__ __align__(16) unsigned short sW1[8 * 8 * 64 * 8];  // 64KB frag-order
    __shared__ __align__(16) unsigned short sW2[4 * 4 * 64 * 8];  // 16KB frag-order
    __shared__ __align__(16) unsigned char  sC[64 * 128 * 4];     // 32KB: Xfrag -> y -> o
    __shared__ __align__(16) unsigned short sHf[4 * 4 * 64 * 8];  // 16KB h frag-order

    unsigned short* sXf = (unsigned short*)sC;
    float* sY = (float*)sC;
    float* sO = (float*)sC;

    //---- stage W1/W2 from blob (coalesced 16B copies) ----
    #pragma unroll
    for (int i = 0; i < 8; ++i)
        *(s8v*)&sW1[(tid + i * 512) * 8] = *(const s8v*)&wblob[(tid + i * 512) * 8];
    #pragma unroll
    for (int i = 0; i < 2; ++i)
        *(s8v*)&sW2[(tid + i * 512) * 8] = *(const s8v*)&wblob[(4096 + tid + i * 512) * 8];

    //---- build X features (wave -> rows wave*8..+7) ----
    #pragma unroll 2
    for (int i = 0; i < 8; ++i) {
        const int r = wave * 8 + i, b = r0 + r;
        const float ue = emb_user[(size_t)user_id[b] * DD + lane];
        const float hp = hist_pool[(size_t)b * DD + lane];
        const int* grow = top_genres + (size_t)b * GG;
        float gacc = 0.f, gw = 0.f;
        #pragma unroll
        for (int g = 0; g < GG; ++g) {
            const int idx = grow[g];
            const float m = (idx > 0) ? 1.f : 0.f;
            gacc = fmaf(m, emb_genre[idx * DD + lane], gacc);
            gw += m;
        }
        const float ug = gacc / (gw + 1e-8f);
        float uc = fmaf(u_avg[b], cont_w[lane * 2 + 0],
                   fmaf(activity[b], cont_w[lane * 2 + 1], cont_b[lane]));
        uc = fmaxf(uc, 0.f);
        PUT_FRAG(sXf, 8, r, lane, ue);
        PUT_FRAG(sXf, 8, r, 64 + lane, hp);
        PUT_FRAG(sXf, 8, r, 128 + lane, ug);
        PUT_FRAG(sXf, 8, r, 192 + lane, uc);
    }
    __syncthreads();

    //---- L1 MFMA: M=64, N=128, K=256. wave: mh=wave>>2, nh=wave&3 ----
    const int mh = wave >> 2, nh = wave & 3;
    f4v acc[2][2];
    const f4v zero4 = {0.f, 0.f, 0.f, 0.f};
    #pragma unroll
    for (int a = 0; a < 2; ++a)
        #pragma unroll
        for (int c = 0; c < 2; ++c) acc[a][c] = zero4;

    #pragma unroll
    for (int ks = 0; ks < 8; ++ks) {
        s8v av[2], bv[2];
        #pragma unroll
        for (int ml = 0; ml < 2; ++ml)
            av[ml] = *(const s8v*)&sXf[(((mh * 2 + ml) * 8 + ks) * 64 + lane) * 8];
        #pragma unroll
        for (int nl = 0; nl < 2; ++nl)
            bv[nl] = *(const s8v*)&sW1[((ks * 8 + nh * 2 + nl) * 64 + lane) * 8];
        #pragma unroll
        for (int ml = 0; ml < 2; ++ml)
            #pragma unroll
            for (int nl = 0; nl < 2; ++nl)
                acc[ml][nl] = __builtin_amdgcn_mfma_f32_16x16x32_bf16(av[ml], bv[nl], acc[ml][nl], 0, 0, 0);
    }
    __syncthreads();

    //---- y = acc + b1 -> sY [64][128] fp32 ----
    #pragma unroll
    for (int ml = 0; ml < 2; ++ml) {
        #pragma unroll
        for (int nl = 0; nl < 2; ++nl) {
            const int n = (nh * 2 + nl) * 16 + (lane & 15);
            const float bb = b1[n];
            #pragma unroll
            for (int rg = 0; rg < 4; ++rg) {
                const int m = (mh * 2 + ml) * 16 + (lane >> 4) * 4 + rg;
                sY[m * 128 + n] = acc[ml][nl][rg] + bb;
            }
        }
    }
    __syncthreads();

    //---- LN + ReLU -> sHf ----
    {
        const float g0 = gam[lane], g1 = gam[lane + 64];
        const float e0 = bet[lane], e1 = bet[lane + 64];
        for (int i = 0; i < 8; ++i) {
            const int r = wave * 8 + i;
            const float a = sY[r * 128 + lane];
            const float c = sY[r * 128 + 64 + lane];
            const float mean = wave_reduce_sum(a + c) * (1.f / 128.f);
            const float da = a - mean, dc = c - mean;
            const float var = wave_reduce_sum(da * da + dc * dc) * (1.f / 128.f);
            const float rstd = rsqrtf(var + 1e-5f);
            const float h0 = fmaxf(fmaf(da * rstd, g0, e0), 0.f);
            const float h1 = fmaxf(fmaf(dc * rstd, g1, e1), 0.f);
            PUT_FRAG(sHf, 4, r, lane, h0);
            PUT_FRAG(sHf, 4, r, 64 + lane, h1);
        }
    }
    __syncthreads();

    //---- L2 MFMA: M=64, N=64, K=128 ----
    f4v acc2[2];
    acc2[0] = zero4; acc2[1] = zero4;
    #pragma unroll
    for (int ks = 0; ks < 4; ++ks) {
        s8v av[2], bv;
        #pragma unroll
        for (int ml = 0; ml < 2; ++ml)
            av[ml] = *(const s8v*)&sHf[(((mh * 2 + ml) * 4 + ks) * 64 + lane) * 8];
        bv = *(const s8v*)&sW2[((ks * 4 + nh) * 64 + lane) * 8];
        #pragma unroll
        for (int ml = 0; ml < 2; ++ml)
            acc2[ml] = __builtin_amdgcn_mfma_f32_16x16x32_bf16(av[ml], bv, acc2[ml], 0, 0, 0);
    }
    #pragma unroll
    for (int ml = 0; ml < 2; ++ml) {
        const int n = nh * 16 + (lane & 15);
        const float bb = b2[n];
        #pragma unroll
        for (int rg = 0; rg < 4; ++rg) {
            const int m = (mh * 2 + ml) * 16 + (lane >> 4) * 4 + rg;
            sO[m * 64 + n] = acc2[ml][rg] + bb;
        }
    }
    __syncthreads();

    //---- l2norm + store ----
    for (int i = 0; i < 8; ++i) {
        const int r = wave * 8 + i;
        const float o = sO[r * 64 + lane];
        const float nrm = sqrtf(wave_reduce_sum(o * o));
        out[(size_t)(r0 + r) * DD + lane] = o / fmaxf(nrm, 1e-12f);
    }
}

//======================================================================
// Kernel 3: item tower (192 -> 128 -> 64), 64 rows/block, 8 waves.
//======================================================================
__global__ __launch_bounds__(512)
void item_tower_kernel(
    const int* __restrict__ item_id, const int* __restrict__ tmdb_genres,
    const float* __restrict__ rel_year, const float* __restrict__ i_avg,
    const float* __restrict__ revenue,
    const float* __restrict__ emb_item, const float* __restrict__ emb_genre,
    const float* __restrict__ cont_w, const float* __restrict__ cont_b,
    const unsigned short* __restrict__ wblob,
    const float* __restrict__ b1,
    const float* __restrict__ gam, const float* __restrict__ bet,
    const float* __restrict__ b2,
    float* __restrict__ out, int B)
{
    const int tid = threadIdx.x, wave = tid >> 6, lane = tid & 63;
    const int r0 = blockIdx.x * 64;

    __shared__ __align__(16) unsigned short sW1[6 * 8 * 64 * 8];  // 48KB
    __shared__ __align__(16) unsigned short sW2[4 * 4 * 64 * 8];  // 16KB
    __shared__ __align__(16) unsigned char  sC[64 * 128 * 4];     // 32KB
    __shared__ __align__(16) unsigned short sHf[4 * 4 * 64 * 8];  // 16KB

    unsigned short* sXf = (unsigned short*)sC;
    float* sY = (float*)sC;
    float* sO = (float*)sC;

    //---- stage W1/W2 from blob ----
    #pragma unroll
    for (int i = 0; i < 6; ++i)
        *(s8v*)&sW1[(tid + i * 512) * 8] = *(const s8v*)&wblob[(5120 + tid + i * 512) * 8];
    #pragma unroll
    for (int i = 0; i < 2; ++i)
        *(s8v*)&sW2[(tid + i * 512) * 8] = *(const s8v*)&wblob[(8192 + tid + i * 512) * 8];

    //---- build X features ----
    #pragma unroll 2
    for (int i = 0; i < 8; ++i) {
        const int r = wave * 8 + i, b = r0 + r;
        const float ie = emb_item[(size_t)item_id[b] * DD + lane];
        const int* grow = tmdb_genres + (size_t)b * GG;
        float gacc = 0.f, gw = 0.f;
        #pragma unroll
        for (int g = 0; g < GG; ++g) {
            const int idx = grow[g];
            const float m = (idx > 0) ? 1.f : 0.f;
            gacc = fmaf(m, emb_genre[idx * DD + lane], gacc);
            gw += m;
        }
        const float ig = gacc / (gw + 1e-8f);
        float ic = fmaf(rel_year[b], cont_w[lane * 3 + 0],
                   fmaf(i_avg[b],   cont_w[lane * 3 + 1],
                   fmaf(revenue[b], cont_w[lane * 3 + 2], cont_b[lane])));
        ic = fmaxf(ic, 0.f);
        PUT_FRAG(sXf, 6, r, lane, ie);
        PUT_FRAG(sXf, 6, r, 64 + lane, ig);
        PUT_FRAG(sXf, 6, r, 128 + lane, ic);
    }
    __syncthreads();

    //---- L1 MFMA: M=64, N=128, K=192 ----
    const int mh = wave >> 2, nh = wave & 3;
    f4v acc[2][2];
    const f4v zero4 = {0.f, 0.f, 0.f, 0.f};
    #pragma unroll
    for (int a = 0; a < 2; ++a)
        #pragma unroll
        for (int c = 0; c < 2; ++c) acc[a][c] = zero4;

    #pragma unroll
    for (int ks = 0; ks < 6; ++ks) {
        s8v av[2], bv[2];
        #pragma unroll
        for (int ml = 0; ml < 2; ++ml)
            av[ml] = *(const s8v*)&sXf[(((mh * 2 + ml) * 6 + ks) * 64 + lane) * 8];
        #pragma unroll
        for (int nl = 0; nl < 2; ++nl)
            bv[nl] = *(const s8v*)&sW1[((ks * 8 + nh * 2 + nl) * 64 + lane) * 8];
        #pragma unroll
        for (int ml = 0; ml < 2; ++ml)
            #pragma unroll
            for (int nl = 0; nl < 2; ++nl)
                acc[ml][nl] = __builtin_amdgcn_mfma_f32_16x16x32_bf16(av[ml], bv[nl], acc[ml][nl], 0, 0, 0);
    }
    __syncthreads();

    #pragma unroll
    for (int ml = 0; ml < 2; ++ml) {
        #pragma unroll
        for (int nl = 0; nl < 2; ++nl) {
            const int n = (nh * 2 + nl) * 16 + (lane & 15);
            const float bb = b1[n];
            #pragma unroll
            for (int rg = 0; rg < 4; ++rg) {
                const int m = (mh * 2 + ml) * 16 + (lane >> 4) * 4 + rg;
                sY[m * 128 + n] = acc[ml][nl][rg] + bb;
            }
        }
    }
    __syncthreads();

    {
        const float g0 = gam[lane], g1 = gam[lane + 64];
        const float e0 = bet[lane], e1 = bet[lane + 64];
        for (int i = 0; i < 8; ++i) {
            const int r = wave * 8 + i;
            const float a = sY[r * 128 + lane];
            const float c = sY[r * 128 + 64 + lane];
            const float mean = wave_reduce_sum(a + c) * (1.f / 128.f);
            const float da = a - mean, dc = c - mean;
            const float var = wave_reduce_sum(da * da + dc * dc) * (1.f / 128.f);
            const float rstd = rsqrtf(var + 1e-5f);
            const float h0 = fmaxf(fmaf(da * rstd, g0, e0), 0.f);
            const float h1 = fmaxf(fmaf(dc * rstd, g1, e1), 0.f);
            PUT_FRAG(sHf, 4, r, lane, h0);
            PUT_FRAG(sHf, 4, r, 64 + lane, h1);
        }
    }
    __syncthreads();

    f4v acc2[2];
    acc2[0] = zero4; acc2[1] = zero4;
    #pragma unroll
    for (int ks = 0; ks < 4; ++ks) {
        s8v av[2], bv;
        #pragma unroll
        for (int ml = 0; ml < 2; ++ml)
            av[ml] = *(const s8v*)&sHf[(((mh * 2 + ml) * 4 + ks) * 64 + lane) * 8];
        bv = *(const s8v*)&sW2[((ks * 4 + nh) * 64 + lane) * 8];
        #pragma unroll
        for (int ml = 0; ml < 2; ++ml)
            acc2[ml] = __builtin_amdgcn_mfma_f32_16x16x32_bf16(av[ml], bv, acc2[ml], 0, 0, 0);
    }
    #pragma unroll
    for (int ml = 0; ml < 2; ++ml) {
        const int n = nh * 16 + (lane & 15);
        const float bb = b2[n];
        #pragma unroll
        for (int rg = 0; rg < 4; ++rg) {
            const int m = (mh * 2 + ml) * 16 + (lane >> 4) * 4 + rg;
            sO[m * 64 + n] = acc2[ml][rg] + bb;
        }
    }
    __syncthreads();

    for (int i = 0; i < 8; ++i) {
        const int r = wave * 8 + i;
        const float o = sO[r * 64 + lane];
        const float nrm = sqrtf(wave_reduce_sum(o * o));
        out[(size_t)B * DD + (size_t)(r0 + r) * DD + lane] = o / fmaxf(nrm, 1e-12f);
    }
}

extern "C" void kernel_launch(void* const* d_in, const int* in_sizes, int n_in,
                              void* d_out, int out_size, void* d_ws, size_t ws_size,
                              hipStream_t stream) {
    const int*   user_id     = (const int*)  d_in[0];
    const int*   history     = (const int*)  d_in[1];
    const int*   top_genres  = (const int*)  d_in[2];
    const int*   item_id     = (const int*)  d_in[3];
    const int*   tmdb_genres = (const int*)  d_in[4];
    const float* ts_diff     = (const float*)d_in[5];
    const float* u_avg       = (const float*)d_in[6];
    const float* activity    = (const float*)d_in[7];
    const float* rel_year    = (const float*)d_in[8];
    const float* i_avg       = (const float*)d_in[9];
    const float* revenue     = (const float*)d_in[10];
    const float* emb_item    = (const float*)d_in[11];
    const float* emb_genre   = (const float*)d_in[12];
    const float* emb_user    = (const float*)d_in[13];
    const float* ut_cont_w   = (const float*)d_in[14];
    const float* ut_cont_b   = (const float*)d_in[15];
    const float* ut_w1       = (const float*)d_in[16];
    const float* ut_b1       = (const float*)d_in[17];
    const float* ut_g        = (const float*)d_in[18];
    const float* ut_be       = (const float*)d_in[19];
    const float* ut_w2       = (const float*)d_in[20];
    const float* ut_b2       = (const float*)d_in[21];
    const float* it_cont_w   = (const float*)d_in[22];
    const float* it_cont_b   = (const float*)d_in[23];
    const float* it_w1       = (const float*)d_in[24];
    const float* it_b1       = (const float*)d_in[25];
    const float* it_g        = (const float*)d_in[26];
    const float* it_be       = (const float*)d_in[27];
    const float* it_w2       = (const float*)d_in[28];
    const float* it_b2       = (const float*)d_in[29];

    const int B = in_sizes[0];                 // 16384
    const int n_item = in_sizes[11];           // V_ITEM * 64

    // workspace layout
    float* hist_pool = (float*)d_ws;                                  // 4MB
    size_t off = (size_t)B * DD * sizeof(float);
    unsigned short* emb_bf16 = (unsigned short*)((char*)d_ws + off);  // 12.8MB
    off += (size_t)n_item * sizeof(unsigned short);
    off = (off + 255) & ~(size_t)255;
    unsigned short* wblob = (unsigned short*)((char*)d_ws + off);     // 144KB

    hipLaunchKernelGGL(prep_kernel, dim3(CONV_BLOCKS + 36), dim3(256), 0, stream,
        emb_item, ut_w1, ut_w2, it_w1, it_w2, emb_bf16, wblob, n_item / 4);

    hipLaunchKernelGGL(hist_pool_kernel, dim3(B / 4), dim3(256), 0, stream,
        history, ts_diff, emb_bf16, hist_pool, B);

    hipLaunchKernelGGL(user_tower_kernel, dim3(B / 64), dim3(512), 0, stream,
        user_id, top_genres, hist_pool, u_avg, activity,
        emb_genre, emb_user, ut_cont_w, ut_cont_b,
        wblob, ut_b1, ut_g, ut_be, ut_b2,
        (float*)d_out, B);

    hipLaunchKernelGGL(item_tower_kernel, dim3(B / 64), dim3(512), 0, stream,
        item_id, tmdb_genres, rel_year, i_avg, revenue,
        emb_item, emb_genre, it_cont_w, it_cont_b,
        wblob, it_b1, it_g, it_be, it_b2,
        (float*)d_out, B);
}

// Round 8
// 67.110 us; speedup vs baseline: 1.7056x; 1.2853x over previous
//
#include <hip/hip_runtime.h>

#define DD 64
#define LL 200
#define LP 256     // LL padded
#define GG 6
#define LAMBDA 0.001f
#define FP8_BLOCKS 3126   // ceil(100001*64/8 / 256)

typedef __attribute__((ext_vector_type(8))) short s8v;   // 8 bf16 (4 VGPRs)
typedef __attribute__((ext_vector_type(4))) float f4v;   // MFMA accumulator
typedef __attribute__((ext_vector_type(2))) float f2v;

__device__ __forceinline__ float wave_reduce_sum(float v) {
    #pragma unroll
    for (int off = 32; off > 0; off >>= 1)
        v += __shfl_xor(v, off, 64);
    return v;
}

__device__ __forceinline__ unsigned short f2bf(float f) {
    union { float f; unsigned int u; } v; v.f = f;
    return (unsigned short)((v.u + 0x7FFFu + ((v.u >> 16) & 1u)) >> 16);  // RNE
}

//======================================================================
// Kernel 0: fused prep.
//  blocks [0, FP8_BLOCKS): emb_item fp32 -> fp8 e4m3 (x64 scale) table
//  blocks [FP8_BLOCKS, +36): 4 MLP weight matrices -> frag-order bf16 blob
//======================================================================
__global__ __launch_bounds__(256)
void prep_kernel(const float* __restrict__ emb_item,
                 const float* __restrict__ ut_w1, const float* __restrict__ ut_w2,
                 const float* __restrict__ it_w1, const float* __restrict__ it_w2,
                 unsigned int* __restrict__ emb8,          // [V*16] uints (4 fp8 each)
                 unsigned short* __restrict__ blob, int n8)
{
    if (blockIdx.x < FP8_BLOCKS) {
        const int i = blockIdx.x * 256 + threadIdx.x;
        if (i < n8) {
            const float4 f0 = *(const float4*)&emb_item[(size_t)i * 8];
            const float4 f1 = *(const float4*)&emb_item[(size_t)i * 8 + 4];
            int lo = __builtin_amdgcn_cvt_pk_fp8_f32(f0.x * 64.f, f0.y * 64.f, 0, false);
            lo     = __builtin_amdgcn_cvt_pk_fp8_f32(f0.z * 64.f, f0.w * 64.f, lo, true);
            int hi = __builtin_amdgcn_cvt_pk_fp8_f32(f1.x * 64.f, f1.y * 64.f, 0, false);
            hi     = __builtin_amdgcn_cvt_pk_fp8_f32(f1.z * 64.f, f1.w * 64.f, hi, true);
            uint2 o; o.x = (unsigned int)lo; o.y = (unsigned int)hi;
            *(uint2*)&emb8[(size_t)i * 2] = o;
        }
        return;
    }
    const int s = (blockIdx.x - FP8_BLOCKS) * 256 + threadIdx.x;   // 0..9215
    if (s >= 9216) return;
    const float* src; int K, NT, r, k8; size_t obase;
    if (s < 4096)      { src = ut_w1; K = 256; NT = 8; r = s >> 5;          k8 = s & 31;          obase = 0; }
    else if (s < 5120) { src = ut_w2; K = 128; NT = 4; r = (s-4096) >> 4;   k8 = (s-4096) & 15;   obase = 4096; }
    else if (s < 8192) { src = it_w1; K = 192; NT = 8; r = (s-5120) / 24;   k8 = (s-5120) % 24;   obase = 5120; }
    else               { src = it_w2; K = 128; NT = 4; r = (s-8192) >> 4;   k8 = (s-8192) & 15;   obase = 8192; }
    const int k = k8 * 8;
    const float4 f0 = *(const float4*)&src[(size_t)r * K + k];
    const float4 f1 = *(const float4*)&src[(size_t)r * K + k + 4];
    const int ks = k >> 5, lg = (k >> 3) & 3;
    const int lp = lg * 16 + (r & 15), nt = r >> 4;
    const size_t slot = obase + (size_t)(ks * NT + nt) * 64 + lp;
    s8v wv;
    wv[0]=(short)f2bf(f0.x); wv[1]=(short)f2bf(f0.y); wv[2]=(short)f2bf(f0.z); wv[3]=(short)f2bf(f0.w);
    wv[4]=(short)f2bf(f1.x); wv[5]=(short)f2bf(f1.y); wv[6]=(short)f2bf(f1.z); wv[7]=(short)f2bf(f1.w);
    *(s8v*)&blob[slot * 8] = wv;
}

//======================================================================
// Kernel 1: history pooling from fp8 table (row = 16 uints = 64B).
// One wave per row; 4 entry-subgroups x 16 lanes; 4B/lane per entry.
//======================================================================
__global__ __launch_bounds__(256)
void hist_pool_kernel(const int* __restrict__ history,
                      const float* __restrict__ ts_diff,
                      const unsigned int* __restrict__ emb8,
                      float* __restrict__ hist_out, int B)
{
    const int wave = threadIdx.x >> 6;
    const int lane = threadIdx.x & 63;
    const int b = blockIdx.x * 4 + wave;
    const int g = lane >> 4;      // entry subgroup 0..3
    const int c = lane & 15;      // uint (4 dims) within row

    __shared__ float2 s_p[4][LP];

    const int*   hrow = history + (size_t)b * LL;
    const float* trow = ts_diff + (size_t)b * LL;

    float wpart = 0.f;
    #pragma unroll
    for (int l = lane; l < LP; l += 64) {
        int idx = 0; float w = 0.f;
        if (l < LL) {
            const int raw = hrow[l];
            if (raw > 0) { w = __expf(-LAMBDA * trow[l]); idx = raw; }
        }
        s_p[wave][l] = make_float2(w, __int_as_float(idx));
        wpart += w;
    }
    const float wsum = wave_reduce_sum(wpart);
    __syncthreads();

    float4 acc = make_float4(0.f, 0.f, 0.f, 0.f);
    #pragma unroll 1
    for (int l0 = 0; l0 < LP; l0 += 64) {
        unsigned int e[16]; float w[16];
        #pragma unroll
        for (int i = 0; i < 16; ++i) {
            const float2 p = s_p[wave][l0 + i * 4 + g];
            w[i] = p.x;
            e[i] = emb8[(size_t)__float_as_int(p.y) * 16 + c];
        }
        #pragma unroll
        for (int i = 0; i < 16; ++i) {
            const f2v lo = __builtin_amdgcn_cvt_pk_f32_fp8((int)e[i], false);
            const f2v hi = __builtin_amdgcn_cvt_pk_f32_fp8((int)e[i], true);
            acc.x = fmaf(w[i], lo[0], acc.x);
            acc.y = fmaf(w[i], lo[1], acc.y);
            acc.z = fmaf(w[i], hi[0], acc.z);
            acc.w = fmaf(w[i], hi[1], acc.w);
        }
    }
    #pragma unroll
    for (int off = 16; off <= 32; off <<= 1) {
        acc.x += __shfl_xor(acc.x, off, 64);
        acc.y += __shfl_xor(acc.y, off, 64);
        acc.z += __shfl_xor(acc.z, off, 64);
        acc.w += __shfl_xor(acc.w, off, 64);
    }
    if (g == 0) {
        const float inv = 0.015625f / (wsum + 1e-8f);   // 1/64 descale folded in
        float4 o = make_float4(acc.x * inv, acc.y * inv, acc.z * inv, acc.w * inv);
        *(float4*)&hist_out[(size_t)b * DD + c * 4] = o;
    }
}

//======================================================================
// X/H fragment slot: A-operand layout for mfma_f32_16x16x32_bf16:
//   lane' = ((d>>3)&3)*16 + (r&15),  j = d&7,  k-step = d>>5
//======================================================================
#define PUT_FRAG(buf, NKS, r, d, val)                                   \
    do {                                                                \
        const int _mt = (r) >> 4, _ks = (d) >> 5;                       \
        const int _lp = (((d) >> 3) & 3) * 16 + ((r) & 15);             \
        (buf)[(((_mt) * (NKS) + _ks) * 64 + _lp) * 8 + ((d) & 7)] = f2bf(val); \
    } while (0)

//======================================================================
// Kernel 2: merged towers. blocks [0,nU): user; [nU,2nU): item.
//======================================================================
__global__ __launch_bounds__(512)
void towers_kernel(
    const int* __restrict__ user_id, const int* __restrict__ top_genres,
    const int* __restrict__ item_id, const int* __restrict__ tmdb_genres,
    const float* __restrict__ hist_pool,
    const float* __restrict__ u_avg, const float* __restrict__ activity,
    const float* __restrict__ rel_year, const float* __restrict__ i_avg,
    const float* __restrict__ revenue,
    const float* __restrict__ emb_item, const float* __restrict__ emb_genre,
    const float* __restrict__ emb_user,
    const float* __restrict__ ut_cont_w, const float* __restrict__ ut_cont_b,
    const float* __restrict__ it_cont_w, const float* __restrict__ it_cont_b,
    const unsigned short* __restrict__ wblob,
    const float* __restrict__ ut_b1, const float* __restrict__ ut_g,
    const float* __restrict__ ut_be, const float* __restrict__ ut_b2,
    const float* __restrict__ it_b1, const float* __restrict__ it_g,
    const float* __restrict__ it_be, const float* __restrict__ it_b2,
    float* __restrict__ out, int B)
{
    const int tid = threadIdx.x, wave = tid >> 6, lane = tid & 63;
    const int nU = B / 64;
    const bool is_user = (int)blockIdx.x < nU;
    const int r0 = (is_user ? blockIdx.x : blockIdx.x - nU) * 64;

    __shared__ __align__(16) unsigned short sW1[8 * 8 * 64 * 8];  // 64KB (item uses 48KB)
    __shared__ __align__(16) unsigned short sW2[4 * 4 * 64 * 8];  // 16KB
    __shared__ __align__(16) unsigned char  sC[64 * 128 * 4];     // 32KB: Xfrag -> y -> o
    __shared__ __align__(16) unsigned short sHf[4 * 4 * 64 * 8];  // 16KB

    unsigned short* sXf = (unsigned short*)sC;
    float* sY = (float*)sC;
    float* sO = (float*)sC;

    const int mh = wave >> 2, nh = wave & 3;
    const f4v zero4 = {0.f, 0.f, 0.f, 0.f};

    if (is_user) {
        //---- stage W1/W2 from blob ----
        #pragma unroll
        for (int i = 0; i < 8; ++i)
            *(s8v*)&sW1[(tid + i * 512) * 8] = *(const s8v*)&wblob[(tid + i * 512) * 8];
        #pragma unroll
        for (int i = 0; i < 2; ++i)
            *(s8v*)&sW2[(tid + i * 512) * 8] = *(const s8v*)&wblob[(4096 + tid + i * 512) * 8];

        //---- build X features ----
        #pragma unroll 2
        for (int i = 0; i < 8; ++i) {
            const int r = wave * 8 + i, b = r0 + r;
            const float ue = emb_user[(size_t)user_id[b] * DD + lane];
            const float hp = hist_pool[(size_t)b * DD + lane];
            const int* grow = top_genres + (size_t)b * GG;
            float gacc = 0.f, gw = 0.f;
            #pragma unroll
            for (int g = 0; g < GG; ++g) {
                const int idx = grow[g];
                const float m = (idx > 0) ? 1.f : 0.f;
                gacc = fmaf(m, emb_genre[idx * DD + lane], gacc);
                gw += m;
            }
            const float ug = gacc / (gw + 1e-8f);
            float uc = fmaf(u_avg[b], ut_cont_w[lane * 2 + 0],
                       fmaf(activity[b], ut_cont_w[lane * 2 + 1], ut_cont_b[lane]));
            uc = fmaxf(uc, 0.f);
            PUT_FRAG(sXf, 8, r, lane, ue);
            PUT_FRAG(sXf, 8, r, 64 + lane, hp);
            PUT_FRAG(sXf, 8, r, 128 + lane, ug);
            PUT_FRAG(sXf, 8, r, 192 + lane, uc);
        }
        __syncthreads();

        //---- L1 MFMA: M=64, N=128, K=256 ----
        f4v acc[2][2];
        #pragma unroll
        for (int a = 0; a < 2; ++a)
            #pragma unroll
            for (int c = 0; c < 2; ++c) acc[a][c] = zero4;
        #pragma unroll
        for (int ks = 0; ks < 8; ++ks) {
            s8v av[2], bv[2];
            #pragma unroll
            for (int ml = 0; ml < 2; ++ml)
                av[ml] = *(const s8v*)&sXf[(((mh * 2 + ml) * 8 + ks) * 64 + lane) * 8];
            #pragma unroll
            for (int nl = 0; nl < 2; ++nl)
                bv[nl] = *(const s8v*)&sW1[((ks * 8 + nh * 2 + nl) * 64 + lane) * 8];
            #pragma unroll
            for (int ml = 0; ml < 2; ++ml)
                #pragma unroll
                for (int nl = 0; nl < 2; ++nl)
                    acc[ml][nl] = __builtin_amdgcn_mfma_f32_16x16x32_bf16(av[ml], bv[nl], acc[ml][nl], 0, 0, 0);
        }
        __syncthreads();

        #pragma unroll
        for (int ml = 0; ml < 2; ++ml) {
            #pragma unroll
            for (int nl = 0; nl < 2; ++nl) {
                const int n = (nh * 2 + nl) * 16 + (lane & 15);
                const float bb = ut_b1[n];
                #pragma unroll
                for (int rg = 0; rg < 4; ++rg) {
                    const int m = (mh * 2 + ml) * 16 + (lane >> 4) * 4 + rg;
                    sY[m * 128 + n] = acc[ml][nl][rg] + bb;
                }
            }
        }
        __syncthreads();

        {
            const float g0 = ut_g[lane], g1 = ut_g[lane + 64];
            const float e0 = ut_be[lane], e1 = ut_be[lane + 64];
            for (int i = 0; i < 8; ++i) {
                const int r = wave * 8 + i;
                const float a = sY[r * 128 + lane];
                const float c = sY[r * 128 + 64 + lane];
                const float mean = wave_reduce_sum(a + c) * (1.f / 128.f);
                const float da = a - mean, dc = c - mean;
                const float var = wave_reduce_sum(da * da + dc * dc) * (1.f / 128.f);
                const float rstd = rsqrtf(var + 1e-5f);
                const float h0 = fmaxf(fmaf(da * rstd, g0, e0), 0.f);
                const float h1 = fmaxf(fmaf(dc * rstd, g1, e1), 0.f);
                PUT_FRAG(sHf, 4, r, lane, h0);
                PUT_FRAG(sHf, 4, r, 64 + lane, h1);
            }
        }
        __syncthreads();

        f4v acc2[2];
        acc2[0] = zero4; acc2[1] = zero4;
        #pragma unroll
        for (int ks = 0; ks < 4; ++ks) {
            s8v av[2], bv;
            #pragma unroll
            for (int ml = 0; ml < 2; ++ml)
                av[ml] = *(const s8v*)&sHf[(((mh * 2 + ml) * 4 + ks) * 64 + lane) * 8];
            bv = *(const s8v*)&sW2[((ks * 4 + nh) * 64 + lane) * 8];
            #pragma unroll
            for (int ml = 0; ml < 2; ++ml)
                acc2[ml] = __builtin_amdgcn_mfma_f32_16x16x32_bf16(av[ml], bv, acc2[ml], 0, 0, 0);
        }
        #pragma unroll
        for (int ml = 0; ml < 2; ++ml) {
            const int n = nh * 16 + (lane & 15);
            const float bb = ut_b2[n];
            #pragma unroll
            for (int rg = 0; rg < 4; ++rg) {
                const int m = (mh * 2 + ml) * 16 + (lane >> 4) * 4 + rg;
                sO[m * 64 + n] = acc2[ml][rg] + bb;
            }
        }
        __syncthreads();

        for (int i = 0; i < 8; ++i) {
            const int r = wave * 8 + i;
            const float o = sO[r * 64 + lane];
            const float nrm = sqrtf(wave_reduce_sum(o * o));
            out[(size_t)(r0 + r) * DD + lane] = o / fmaxf(nrm, 1e-12f);
        }
    } else {
        //================= item tower =================
        #pragma unroll
        for (int i = 0; i < 6; ++i)
            *(s8v*)&sW1[(tid + i * 512) * 8] = *(const s8v*)&wblob[(5120 + tid + i * 512) * 8];
        #pragma unroll
        for (int i = 0; i < 2; ++i)
            *(s8v*)&sW2[(tid + i * 512) * 8] = *(const s8v*)&wblob[(8192 + tid + i * 512) * 8];

        #pragma unroll 2
        for (int i = 0; i < 8; ++i) {
            const int r = wave * 8 + i, b = r0 + r;
            const float ie = emb_item[(size_t)item_id[b] * DD + lane];
            const int* grow = tmdb_genres + (size_t)b * GG;
            float gacc = 0.f, gw = 0.f;
            #pragma unroll
            for (int g = 0; g < GG; ++g) {
                const int idx = grow[g];
                const float m = (idx > 0) ? 1.f : 0.f;
                gacc = fmaf(m, emb_genre[idx * DD + lane], gacc);
                gw += m;
            }
            const float ig = gacc / (gw + 1e-8f);
            float ic = fmaf(rel_year[b], it_cont_w[lane * 3 + 0],
                       fmaf(i_avg[b],   it_cont_w[lane * 3 + 1],
                       fmaf(revenue[b], it_cont_w[lane * 3 + 2], it_cont_b[lane])));
            ic = fmaxf(ic, 0.f);
            PUT_FRAG(sXf, 6, r, lane, ie);
            PUT_FRAG(sXf, 6, r, 64 + lane, ig);
            PUT_FRAG(sXf, 6, r, 128 + lane, ic);
        }
        __syncthreads();

        f4v acc[2][2];
        #pragma unroll
        for (int a = 0; a < 2; ++a)
            #pragma unroll
            for (int c = 0; c < 2; ++c) acc[a][c] = zero4;
        #pragma unroll
        for (int ks = 0; ks < 6; ++ks) {
            s8v av[2], bv[2];
            #pragma unroll
            for (int ml = 0; ml < 2; ++ml)
                av[ml] = *(const s8v*)&sXf[(((mh * 2 + ml) * 6 + ks) * 64 + lane) * 8];
            #pragma unroll
            for (int nl = 0; nl < 2; ++nl)
                bv[nl] = *(const s8v*)&sW1[((ks * 8 + nh * 2 + nl) * 64 + lane) * 8];
            #pragma unroll
            for (int ml = 0; ml < 2; ++ml)
                #pragma unroll
                for (int nl = 0; nl < 2; ++nl)
                    acc[ml][nl] = __builtin_amdgcn_mfma_f32_16x16x32_bf16(av[ml], bv[nl], acc[ml][nl], 0, 0, 0);
        }
        __syncthreads();

        #pragma unroll
        for (int ml = 0; ml < 2; ++ml) {
            #pragma unroll
            for (int nl = 0; nl < 2; ++nl) {
                const int n = (nh * 2 + nl) * 16 + (lane & 15);
                const float bb = it_b1[n];
                #pragma unroll
                for (int rg = 0; rg < 4; ++rg) {
                    const int m = (mh * 2 + ml) * 16 + (lane >> 4) * 4 + rg;
                    sY[m * 128 + n] = acc[ml][nl][rg] + bb;
                }
            }
        }
        __syncthreads();

        {
            const float g0 = it_g[lane], g1 = it_g[lane + 64];
            const float e0 = it_be[lane], e1 = it_be[lane + 64];
            for (int i = 0; i < 8; ++i) {
                const int r = wave * 8 + i;
                const float a = sY[r * 128 + lane];
                const float c = sY[r * 128 + 64 + lane];
                const float mean = wave_reduce_sum(a + c) * (1.f / 128.f);
                const float da = a - mean, dc = c - mean;
                const float var = wave_reduce_sum(da * da + dc * dc) * (1.f / 128.f);
                const float rstd = rsqrtf(var + 1e-5f);
                const float h0 = fmaxf(fmaf(da * rstd, g0, e0), 0.f);
                const float h1 = fmaxf(fmaf(dc * rstd, g1, e1), 0.f);
                PUT_FRAG(sHf, 4, r, lane, h0);
                PUT_FRAG(sHf, 4, r, 64 + lane, h1);
            }
        }
        __syncthreads();

        f4v acc2[2];
        acc2[0] = zero4; acc2[1] = zero4;
        #pragma unroll
        for (int ks = 0; ks < 4; ++ks) {
            s8v av[2], bv;
            #pragma unroll
            for (int ml = 0; ml < 2; ++ml)
                av[ml] = *(const s8v*)&sHf[(((mh * 2 + ml) * 4 + ks) * 64 + lane) * 8];
            bv = *(const s8v*)&sW2[((ks * 4 + nh) * 64 + lane) * 8];
            #pragma unroll
            for (int ml = 0; ml < 2; ++ml)
                acc2[ml] = __builtin_amdgcn_mfma_f32_16x16x32_bf16(av[ml], bv, acc2[ml], 0, 0, 0);
        }
        #pragma unroll
        for (int ml = 0; ml < 2; ++ml) {
            const int n = nh * 16 + (lane & 15);
            const float bb = it_b2[n];
            #pragma unroll
            for (int rg = 0; rg < 4; ++rg) {
                const int m = (mh * 2 + ml) * 16 + (lane >> 4) * 4 + rg;
                sO[m * 64 + n] = acc2[ml][rg] + bb;
            }
        }
        __syncthreads();

        for (int i = 0; i < 8; ++i) {
            const int r = wave * 8 + i;
            const float o = sO[r * 64 + lane];
            const float nrm = sqrtf(wave_reduce_sum(o * o));
            out[(size_t)B * DD + (size_t)(r0 + r) * DD + lane] = o / fmaxf(nrm, 1e-12f);
        }
    }
}

extern "C" void kernel_launch(void* const* d_in, const int* in_sizes, int n_in,
                              void* d_out, int out_size, void* d_ws, size_t ws_size,
                              hipStream_t stream) {
    const int*   user_id     = (const int*)  d_in[0];
    const int*   history     = (const int*)  d_in[1];
    const int*   top_genres  = (const int*)  d_in[2];
    const int*   item_id     = (const int*)  d_in[3];
    const int*   tmdb_genres = (const int*)  d_in[4];
    const float* ts_diff     = (const float*)d_in[5];
    const float* u_avg       = (const float*)d_in[6];
    const float* activity    = (const float*)d_in[7];
    const float* rel_year    = (const float*)d_in[8];
    const float* i_avg       = (const float*)d_in[9];
    const float* revenue     = (const float*)d_in[10];
    const float* emb_item    = (const float*)d_in[11];
    const float* emb_genre   = (const float*)d_in[12];
    const float* emb_user    = (const float*)d_in[13];
    const float* ut_cont_w   = (const float*)d_in[14];
    const float* ut_cont_b   = (const float*)d_in[15];
    const float* ut_w1       = (const float*)d_in[16];
    const float* ut_b1       = (const float*)d_in[17];
    const float* ut_g        = (const float*)d_in[18];
    const float* ut_be       = (const float*)d_in[19];
    const float* ut_w2       = (const float*)d_in[20];
    const float* ut_b2       = (const float*)d_in[21];
    const float* it_cont_w   = (const float*)d_in[22];
    const float* it_cont_b   = (const float*)d_in[23];
    const float* it_w1       = (const float*)d_in[24];
    const float* it_b1       = (const float*)d_in[25];
    const float* it_g        = (const float*)d_in[26];
    const float* it_be       = (const float*)d_in[27];
    const float* it_w2       = (const float*)d_in[28];
    const float* it_b2       = (const float*)d_in[29];

    const int B = in_sizes[0];                 // 16384
    const int n_item = in_sizes[11];           // V_ITEM * 64

    // workspace layout
    float* hist_pool = (float*)d_ws;                                  // 4MB
    size_t off = (size_t)B * DD * sizeof(float);
    unsigned int* emb8 = (unsigned int*)((char*)d_ws + off);          // 6.4MB
    off += (size_t)(n_item / 4) * sizeof(unsigned int);
    off = (off + 255) & ~(size_t)255;
    unsigned short* wblob = (unsigned short*)((char*)d_ws + off);     // 144KB

    hipLaunchKernelGGL(prep_kernel, dim3(FP8_BLOCKS + 36), dim3(256), 0, stream,
        emb_item, ut_w1, ut_w2, it_w1, it_w2, emb8, wblob, n_item / 8);

    hipLaunchKernelGGL(hist_pool_kernel, dim3(B / 4), dim3(256), 0, stream,
        history, ts_diff, emb8, hist_pool, B);

    hipLaunchKernelGGL(towers_kernel, dim3(2 * (B / 64)), dim3(512), 0, stream,
        user_id, top_genres, item_id, tmdb_genres, hist_pool,
        u_avg, activity, rel_year, i_avg, revenue,
        emb_item, emb_genre, emb_user,
        ut_cont_w, ut_cont_b, it_cont_w, it_cont_b,
        wblob, ut_b1, ut_g, ut_be, ut_b2, it_b1, it_g, it_be, it_b2,
        (float*)d_out, B);
}

// Round 9
// 66.272 us; speedup vs baseline: 1.7271x; 1.0127x over previous
//
#include <hip/hip_runtime.h>

#define DD 64
#define LL 200
#define LP 256     // LL padded
#define GG 6
#define LAMBDA 0.001f
#define FP8_BLOCKS 3126   // ceil(100001*64/8 / 256)

typedef __attribute__((ext_vector_type(8))) short s8v;   // 8 bf16 (4 VGPRs)
typedef __attribute__((ext_vector_type(4))) float f4v;   // MFMA accumulator
typedef __attribute__((ext_vector_type(2))) float f2v;

__device__ __forceinline__ float wave_reduce_sum(float v) {
    #pragma unroll
    for (int off = 32; off > 0; off >>= 1)
        v += __shfl_xor(v, off, 64);
    return v;
}

__device__ __forceinline__ unsigned short f2bf(float f) {
    union { float f; unsigned int u; } v; v.f = f;
    return (unsigned short)((v.u + 0x7FFFu + ((v.u >> 16) & 1u)) >> 16);  // RNE
}

//======================================================================
// Kernel 0: fused prep.
//  blocks [0, FP8_BLOCKS): emb_item fp32 -> fp8 e4m3 (x64 scale) table
//  blocks [FP8_BLOCKS, +36): 4 MLP weight matrices -> frag-order bf16 blob
//======================================================================
__global__ __launch_bounds__(256)
void prep_kernel(const float* __restrict__ emb_item,
                 const float* __restrict__ ut_w1, const float* __restrict__ ut_w2,
                 const float* __restrict__ it_w1, const float* __restrict__ it_w2,
                 unsigned int* __restrict__ emb8,          // [V*16] uints (4 fp8 each)
                 unsigned short* __restrict__ blob, int n8)
{
    if (blockIdx.x < FP8_BLOCKS) {
        const int i = blockIdx.x * 256 + threadIdx.x;
        if (i < n8) {
            const float4 f0 = *(const float4*)&emb_item[(size_t)i * 8];
            const float4 f1 = *(const float4*)&emb_item[(size_t)i * 8 + 4];
            int lo = __builtin_amdgcn_cvt_pk_fp8_f32(f0.x * 64.f, f0.y * 64.f, 0, false);
            lo     = __builtin_amdgcn_cvt_pk_fp8_f32(f0.z * 64.f, f0.w * 64.f, lo, true);
            int hi = __builtin_amdgcn_cvt_pk_fp8_f32(f1.x * 64.f, f1.y * 64.f, 0, false);
            hi     = __builtin_amdgcn_cvt_pk_fp8_f32(f1.z * 64.f, f1.w * 64.f, hi, true);
            uint2 o; o.x = (unsigned int)lo; o.y = (unsigned int)hi;
            *(uint2*)&emb8[(size_t)i * 2] = o;
        }
        return;
    }
    const int s = (blockIdx.x - FP8_BLOCKS) * 256 + threadIdx.x;   // 0..9215
    if (s >= 9216) return;
    const float* src; int K, NT, r, k8; size_t obase;
    if (s < 4096)      { src = ut_w1; K = 256; NT = 8; r = s >> 5;          k8 = s & 31;          obase = 0; }
    else if (s < 5120) { src = ut_w2; K = 128; NT = 4; r = (s-4096) >> 4;   k8 = (s-4096) & 15;   obase = 4096; }
    else if (s < 8192) { src = it_w1; K = 192; NT = 8; r = (s-5120) / 24;   k8 = (s-5120) % 24;   obase = 5120; }
    else               { src = it_w2; K = 128; NT = 4; r = (s-8192) >> 4;   k8 = (s-8192) & 15;   obase = 8192; }
    const int k = k8 * 8;
    const float4 f0 = *(const float4*)&src[(size_t)r * K + k];
    const float4 f1 = *(const float4*)&src[(size_t)r * K + k + 4];
    const int ks = k >> 5, lg = (k >> 3) & 3;
    const int lp = lg * 16 + (r & 15), nt = r >> 4;
    const size_t slot = obase + (size_t)(ks * NT + nt) * 64 + lp;
    s8v wv;
    wv[0]=(short)f2bf(f0.x); wv[1]=(short)f2bf(f0.y); wv[2]=(short)f2bf(f0.z); wv[3]=(short)f2bf(f0.w);
    wv[4]=(short)f2bf(f1.x); wv[5]=(short)f2bf(f1.y); wv[6]=(short)f2bf(f1.z); wv[7]=(short)f2bf(f1.w);
    *(s8v*)&blob[slot * 8] = wv;
}

//======================================================================
// Kernel 1: history pooling from fp8 table (row = 64B).
// One wave per row; 8 entry-subgroups x 8 lanes; 8B (uint2) per lane.
//======================================================================
__global__ __launch_bounds__(256)
void hist_pool_kernel(const int* __restrict__ history,
                      const float* __restrict__ ts_diff,
                      const uint2* __restrict__ emb8,     // row = 8 uint2
                      float* __restrict__ hist_out, int B)
{
    const int wave = threadIdx.x >> 6;
    const int lane = threadIdx.x & 63;
    const int b = blockIdx.x * 4 + wave;
    const int grp = lane >> 3;    // entry subgroup 0..7
    const int c8 = lane & 7;      // 8-dim chunk within row

    __shared__ float2 s_p[4][LP];

    const int*   hrow = history + (size_t)b * LL;
    const float* trow = ts_diff + (size_t)b * LL;

    float wpart = 0.f;
    #pragma unroll
    for (int l = lane; l < LP; l += 64) {
        int idx = 0; float w = 0.f;
        if (l < LL) {
            const int raw = hrow[l];
            if (raw > 0) { w = __expf(-LAMBDA * trow[l]); idx = raw; }
        }
        s_p[wave][l] = make_float2(w, __int_as_float(idx));
        wpart += w;
    }
    const float wsum = wave_reduce_sum(wpart);
    __syncthreads();

    float a[8];
    #pragma unroll
    for (int j = 0; j < 8; ++j) a[j] = 0.f;

    #pragma unroll 1
    for (int l0 = 0; l0 < LP; l0 += 128) {
        uint2 e[16]; float w[16];
        #pragma unroll
        for (int i = 0; i < 16; ++i) {
            const float2 p = s_p[wave][l0 + i * 8 + grp];
            w[i] = p.x;
            e[i] = emb8[(size_t)__float_as_int(p.y) * 8 + c8];
        }
        #pragma unroll
        for (int i = 0; i < 16; ++i) {
            const f2v d01 = __builtin_amdgcn_cvt_pk_f32_fp8((int)e[i].x, false);
            const f2v d23 = __builtin_amdgcn_cvt_pk_f32_fp8((int)e[i].x, true);
            const f2v d45 = __builtin_amdgcn_cvt_pk_f32_fp8((int)e[i].y, false);
            const f2v d67 = __builtin_amdgcn_cvt_pk_f32_fp8((int)e[i].y, true);
            a[0] = fmaf(w[i], d01[0], a[0]);
            a[1] = fmaf(w[i], d01[1], a[1]);
            a[2] = fmaf(w[i], d23[0], a[2]);
            a[3] = fmaf(w[i], d23[1], a[3]);
            a[4] = fmaf(w[i], d45[0], a[4]);
            a[5] = fmaf(w[i], d45[1], a[5]);
            a[6] = fmaf(w[i], d67[0], a[6]);
            a[7] = fmaf(w[i], d67[1], a[7]);
        }
    }
    // reduce across the 8 entry-subgroups (lanes differing in bits 3,4,5)
    #pragma unroll
    for (int off = 8; off <= 32; off <<= 1)
        #pragma unroll
        for (int j = 0; j < 8; ++j)
            a[j] += __shfl_xor(a[j], off, 64);

    if (grp == 0) {
        const float inv = 0.015625f / (wsum + 1e-8f);   // 1/64 descale folded in
        float4 o0 = make_float4(a[0]*inv, a[1]*inv, a[2]*inv, a[3]*inv);
        float4 o1 = make_float4(a[4]*inv, a[5]*inv, a[6]*inv, a[7]*inv);
        *(float4*)&hist_out[(size_t)b * DD + c8 * 8]     = o0;
        *(float4*)&hist_out[(size_t)b * DD + c8 * 8 + 4] = o1;
    }
}

//======================================================================
// X/H fragment slot: A-operand layout for mfma_f32_16x16x32_bf16:
//   lane' = ((d>>3)&3)*16 + (r&15),  j = d&7,  k-step = d>>5
//======================================================================
#define PUT_FRAG(buf, NKS, r, d, val)                                   \
    do {                                                                \
        const int _mt = (r) >> 4, _ks = (d) >> 5;                       \
        const int _lp = (((d) >> 3) & 3) * 16 + ((r) & 15);             \
        (buf)[(((_mt) * (NKS) + _ks) * 64 + _lp) * 8 + ((d) & 7)] = f2bf(val); \
    } while (0)

//======================================================================
// Kernel 2: merged towers, weights read DIRECTLY from global blob
// (frag-ordered, L2-hot) -> LDS = 48KB -> up to 3 blocks/CU.
//======================================================================
__global__ __launch_bounds__(512)
void towers_kernel(
    const int* __restrict__ user_id, const int* __restrict__ top_genres,
    const int* __restrict__ item_id, const int* __restrict__ tmdb_genres,
    const float* __restrict__ hist_pool,
    const float* __restrict__ u_avg, const float* __restrict__ activity,
    const float* __restrict__ rel_year, const float* __restrict__ i_avg,
    const float* __restrict__ revenue,
    const float* __restrict__ emb_item, const float* __restrict__ emb_genre,
    const float* __restrict__ emb_user,
    const float* __restrict__ ut_cont_w, const float* __restrict__ ut_cont_b,
    const float* __restrict__ it_cont_w, const float* __restrict__ it_cont_b,
    const unsigned short* __restrict__ wblob,
    const float* __restrict__ ut_b1, const float* __restrict__ ut_g,
    const float* __restrict__ ut_be, const float* __restrict__ ut_b2,
    const float* __restrict__ it_b1, const float* __restrict__ it_g,
    const float* __restrict__ it_be, const float* __restrict__ it_b2,
    float* __restrict__ out, int B)
{
    const int tid = threadIdx.x, wave = tid >> 6, lane = tid & 63;
    const int nU = B / 64;
    const bool is_user = (int)blockIdx.x < nU;
    const int r0 = (is_user ? blockIdx.x : blockIdx.x - nU) * 64;

    __shared__ __align__(16) unsigned char  sC[64 * 128 * 4];     // 32KB: Xfrag -> y -> o
    __shared__ __align__(16) unsigned short sHf[4 * 4 * 64 * 8];  // 16KB

    unsigned short* sXf = (unsigned short*)sC;
    float* sY = (float*)sC;
    float* sO = (float*)sC;

    const int mh = wave >> 2, nh = wave & 3;
    const f4v zero4 = {0.f, 0.f, 0.f, 0.f};

    if (is_user) {
        //---- build X features ----
        #pragma unroll 2
        for (int i = 0; i < 8; ++i) {
            const int r = wave * 8 + i, b = r0 + r;
            const float ue = emb_user[(size_t)user_id[b] * DD + lane];
            const float hp = hist_pool[(size_t)b * DD + lane];
            const int* grow = top_genres + (size_t)b * GG;
            float gacc = 0.f, gw = 0.f;
            #pragma unroll
            for (int g = 0; g < GG; ++g) {
                const int idx = grow[g];
                const float m = (idx > 0) ? 1.f : 0.f;
                gacc = fmaf(m, emb_genre[idx * DD + lane], gacc);
                gw += m;
            }
            const float ug = gacc / (gw + 1e-8f);
            float uc = fmaf(u_avg[b], ut_cont_w[lane * 2 + 0],
                       fmaf(activity[b], ut_cont_w[lane * 2 + 1], ut_cont_b[lane]));
            uc = fmaxf(uc, 0.f);
            PUT_FRAG(sXf, 8, r, lane, ue);
            PUT_FRAG(sXf, 8, r, 64 + lane, hp);
            PUT_FRAG(sXf, 8, r, 128 + lane, ug);
            PUT_FRAG(sXf, 8, r, 192 + lane, uc);
        }
        __syncthreads();

        //---- L1 MFMA: M=64, N=128, K=256; B-operand from global blob ----
        f4v acc[2][2];
        #pragma unroll
        for (int a = 0; a < 2; ++a)
            #pragma unroll
            for (int c = 0; c < 2; ++c) acc[a][c] = zero4;
        #pragma unroll
        for (int ks = 0; ks < 8; ++ks) {
            s8v av[2], bv[2];
            #pragma unroll
            for (int ml = 0; ml < 2; ++ml)
                av[ml] = *(const s8v*)&sXf[(((mh * 2 + ml) * 8 + ks) * 64 + lane) * 8];
            #pragma unroll
            for (int nl = 0; nl < 2; ++nl)
                bv[nl] = *(const s8v*)&wblob[((ks * 8 + nh * 2 + nl) * 64 + lane) * 8];
            #pragma unroll
            for (int ml = 0; ml < 2; ++ml)
                #pragma unroll
                for (int nl = 0; nl < 2; ++nl)
                    acc[ml][nl] = __builtin_amdgcn_mfma_f32_16x16x32_bf16(av[ml], bv[nl], acc[ml][nl], 0, 0, 0);
        }
        __syncthreads();

        #pragma unroll
        for (int ml = 0; ml < 2; ++ml) {
            #pragma unroll
            for (int nl = 0; nl < 2; ++nl) {
                const int n = (nh * 2 + nl) * 16 + (lane & 15);
                const float bb = ut_b1[n];
                #pragma unroll
                for (int rg = 0; rg < 4; ++rg) {
                    const int m = (mh * 2 + ml) * 16 + (lane >> 4) * 4 + rg;
                    sY[m * 128 + n] = acc[ml][nl][rg] + bb;
                }
            }
        }
        __syncthreads();

        {
            const float g0 = ut_g[lane], g1 = ut_g[lane + 64];
            const float e0 = ut_be[lane], e1 = ut_be[lane + 64];
            for (int i = 0; i < 8; ++i) {
                const int r = wave * 8 + i;
                const float a = sY[r * 128 + lane];
                const float c = sY[r * 128 + 64 + lane];
                const float mean = wave_reduce_sum(a + c) * (1.f / 128.f);
                const float da = a - mean, dc = c - mean;
                const float var = wave_reduce_sum(da * da + dc * dc) * (1.f / 128.f);
                const float rstd = rsqrtf(var + 1e-5f);
                const float h0 = fmaxf(fmaf(da * rstd, g0, e0), 0.f);
                const float h1 = fmaxf(fmaf(dc * rstd, g1, e1), 0.f);
                PUT_FRAG(sHf, 4, r, lane, h0);
                PUT_FRAG(sHf, 4, r, 64 + lane, h1);
            }
        }
        __syncthreads();

        f4v acc2[2];
        acc2[0] = zero4; acc2[1] = zero4;
        #pragma unroll
        for (int ks = 0; ks < 4; ++ks) {
            s8v av[2], bv;
            #pragma unroll
            for (int ml = 0; ml < 2; ++ml)
                av[ml] = *(const s8v*)&sHf[(((mh * 2 + ml) * 4 + ks) * 64 + lane) * 8];
            bv = *(const s8v*)&wblob[(4096 + (ks * 4 + nh) * 64 + lane) * 8];
            #pragma unroll
            for (int ml = 0; ml < 2; ++ml)
                acc2[ml] = __builtin_amdgcn_mfma_f32_16x16x32_bf16(av[ml], bv, acc2[ml], 0, 0, 0);
        }
        #pragma unroll
        for (int ml = 0; ml < 2; ++ml) {
            const int n = nh * 16 + (lane & 15);
            const float bb = ut_b2[n];
            #pragma unroll
            for (int rg = 0; rg < 4; ++rg) {
                const int m = (mh * 2 + ml) * 16 + (lane >> 4) * 4 + rg;
                sO[m * 64 + n] = acc2[ml][rg] + bb;
            }
        }
        __syncthreads();

        for (int i = 0; i < 8; ++i) {
            const int r = wave * 8 + i;
            const float o = sO[r * 64 + lane];
            const float nrm = sqrtf(wave_reduce_sum(o * o));
            out[(size_t)(r0 + r) * DD + lane] = o / fmaxf(nrm, 1e-12f);
        }
    } else {
        //================= item tower =================
        #pragma unroll 2
        for (int i = 0; i < 8; ++i) {
            const int r = wave * 8 + i, b = r0 + r;
            const float ie = emb_item[(size_t)item_id[b] * DD + lane];
            const int* grow = tmdb_genres + (size_t)b * GG;
            float gacc = 0.f, gw = 0.f;
            #pragma unroll
            for (int g = 0; g < GG; ++g) {
                const int idx = grow[g];
                const float m = (idx > 0) ? 1.f : 0.f;
                gacc = fmaf(m, emb_genre[idx * DD + lane], gacc);
                gw += m;
            }
            const float ig = gacc / (gw + 1e-8f);
            float ic = fmaf(rel_year[b], it_cont_w[lane * 3 + 0],
                       fmaf(i_avg[b],   it_cont_w[lane * 3 + 1],
                       fmaf(revenue[b], it_cont_w[lane * 3 + 2], it_cont_b[lane])));
            ic = fmaxf(ic, 0.f);
            PUT_FRAG(sXf, 6, r, lane, ie);
            PUT_FRAG(sXf, 6, r, 64 + lane, ig);
            PUT_FRAG(sXf, 6, r, 128 + lane, ic);
        }
        __syncthreads();

        f4v acc[2][2];
        #pragma unroll
        for (int a = 0; a < 2; ++a)
            #pragma unroll
            for (int c = 0; c < 2; ++c) acc[a][c] = zero4;
        #pragma unroll
        for (int ks = 0; ks < 6; ++ks) {
            s8v av[2], bv[2];
            #pragma unroll
            for (int ml = 0; ml < 2; ++ml)
                av[ml] = *(const s8v*)&sXf[(((mh * 2 + ml) * 6 + ks) * 64 + lane) * 8];
            #pragma unroll
            for (int nl = 0; nl < 2; ++nl)
                bv[nl] = *(const s8v*)&wblob[(5120 + (ks * 8 + nh * 2 + nl) * 64 + lane) * 8];
            #pragma unroll
            for (int ml = 0; ml < 2; ++ml)
                #pragma unroll
                for (int nl = 0; nl < 2; ++nl)
                    acc[ml][nl] = __builtin_amdgcn_mfma_f32_16x16x32_bf16(av[ml], bv[nl], acc[ml][nl], 0, 0, 0);
        }
        __syncthreads();

        #pragma unroll
        for (int ml = 0; ml < 2; ++ml) {
            #pragma unroll
            for (int nl = 0; nl < 2; ++nl) {
                const int n = (nh * 2 + nl) * 16 + (lane & 15);
                const float bb = it_b1[n];
                #pragma unroll
                for (int rg = 0; rg < 4; ++rg) {
                    const int m = (mh * 2 + ml) * 16 + (lane >> 4) * 4 + rg;
                    sY[m * 128 + n] = acc[ml][nl][rg] + bb;
                }
            }
        }
        __syncthreads();

        {
            const float g0 = it_g[lane], g1 = it_g[lane + 64];
            const float e0 = it_be[lane], e1 = it_be[lane + 64];
            for (int i = 0; i < 8; ++i) {
                const int r = wave * 8 + i;
                const float a = sY[r * 128 + lane];
                const float c = sY[r * 128 + 64 + lane];
                const float mean = wave_reduce_sum(a + c) * (1.f / 128.f);
                const float da = a - mean, dc = c - mean;
                const float var = wave_reduce_sum(da * da + dc * dc) * (1.f / 128.f);
                const float rstd = rsqrtf(var + 1e-5f);
                const float h0 = fmaxf(fmaf(da * rstd, g0, e0), 0.f);
                const float h1 = fmaxf(fmaf(dc * rstd, g1, e1), 0.f);
                PUT_FRAG(sHf, 4, r, lane, h0);
                PUT_FRAG(sHf, 4, r, 64 + lane, h1);
            }
        }
        __syncthreads();

        f4v acc2[2];
        acc2[0] = zero4; acc2[1] = zero4;
        #pragma unroll
        for (int ks = 0; ks < 4; ++ks) {
            s8v av[2], bv;
            #pragma unroll
            for (int ml = 0; ml < 2; ++ml)
                av[ml] = *(const s8v*)&sHf[(((mh * 2 + ml) * 4 + ks) * 64 + lane) * 8];
            bv = *(const s8v*)&wblob[(8192 + (ks * 4 + nh) * 64 + lane) * 8];
            #pragma unroll
            for (int ml = 0; ml < 2; ++ml)
                acc2[ml] = __builtin_amdgcn_mfma_f32_16x16x32_bf16(av[ml], bv, acc2[ml], 0, 0, 0);
        }
        #pragma unroll
        for (int ml = 0; ml < 2; ++ml) {
            const int n = nh * 16 + (lane & 15);
            const float bb = it_b2[n];
            #pragma unroll
            for (int rg = 0; rg < 4; ++rg) {
                const int m = (mh * 2 + ml) * 16 + (lane >> 4) * 4 + rg;
                sO[m * 64 + n] = acc2[ml][rg] + bb;
            }
        }
        __syncthreads();

        for (int i = 0; i < 8; ++i) {
            const int r = wave * 8 + i;
            const float o = sO[r * 64 + lane];
            const float nrm = sqrtf(wave_reduce_sum(o * o));
            out[(size_t)B * DD + (size_t)(r0 + r) * DD + lane] = o / fmaxf(nrm, 1e-12f);
        }
    }
}

extern "C" void kernel_launch(void* const* d_in, const int* in_sizes, int n_in,
                              void* d_out, int out_size, void* d_ws, size_t ws_size,
                              hipStream_t stream) {
    const int*   user_id     = (const int*)  d_in[0];
    const int*   history     = (const int*)  d_in[1];
    const int*   top_genres  = (const int*)  d_in[2];
    const int*   item_id     = (const int*)  d_in[3];
    const int*   tmdb_genres = (const int*)  d_in[4];
    const float* ts_diff     = (const float*)d_in[5];
    const float* u_avg       = (const float*)d_in[6];
    const float* activity    = (const float*)d_in[7];
    const float* rel_year    = (const float*)d_in[8];
    const float* i_avg       = (const float*)d_in[9];
    const float* revenue     = (const float*)d_in[10];
    const float* emb_item    = (const float*)d_in[11];
    const float* emb_genre   = (const float*)d_in[12];
    const float* emb_user    = (const float*)d_in[13];
    const float* ut_cont_w   = (const float*)d_in[14];
    const float* ut_cont_b   = (const float*)d_in[15];
    const float* ut_w1       = (const float*)d_in[16];
    const float* ut_b1       = (const float*)d_in[17];
    const float* ut_g        = (const float*)d_in[18];
    const float* ut_be       = (const float*)d_in[19];
    const float* ut_w2       = (const float*)d_in[20];
    const float* ut_b2       = (const float*)d_in[21];
    const float* it_cont_w   = (const float*)d_in[22];
    const float* it_cont_b   = (const float*)d_in[23];
    const float* it_w1       = (const float*)d_in[24];
    const float* it_b1       = (const float*)d_in[25];
    const float* it_g        = (const float*)d_in[26];
    const float* it_be       = (const float*)d_in[27];
    const float* it_w2       = (const float*)d_in[28];
    const float* it_b2       = (const float*)d_in[29];

    const int B = in_sizes[0];                 // 16384
    const int n_item = in_sizes[11];           // V_ITEM * 64

    // workspace layout
    float* hist_pool = (float*)d_ws;                                  // 4MB
    size_t off = (size_t)B * DD * sizeof(float);
    unsigned int* emb8 = (unsigned int*)((char*)d_ws + off);          // 6.4MB
    off += (size_t)(n_item / 4) * sizeof(unsigned int);
    off = (off + 255) & ~(size_t)255;
    unsigned short* wblob = (unsigned short*)((char*)d_ws + off);     // 144KB

    hipLaunchKernelGGL(prep_kernel, dim3(FP8_BLOCKS + 36), dim3(256), 0, stream,
        emb_item, ut_w1, ut_w2, it_w1, it_w2, emb8, wblob, n_item / 8);

    hipLaunchKernelGGL(hist_pool_kernel, dim3(B / 4), dim3(256), 0, stream,
        history, ts_diff, (const uint2*)emb8, hist_pool, B);

    hipLaunchKernelGGL(towers_kernel, dim3(2 * (B / 64)), dim3(512), 0, stream,
        user_id, top_genres, item_id, tmdb_genres, hist_pool,
        u_avg, activity, rel_year, i_avg, revenue,
        emb_item, emb_genre, emb_user,
        ut_cont_w, ut_cont_b, it_cont_w, it_cont_b,
        wblob, ut_b1, ut_g, ut_be, ut_b2, it_b1, it_g, it_be, it_b2,
        (float*)d_out, B);
}